// Round 10
// baseline (778.977 us; speedup 1.0000x reference)
//
#include <hip/hip_runtime.h>
#include <hip/hip_bf16.h>
#include <math.h>

typedef __bf16 bf16x8 __attribute__((ext_vector_type(8)));
typedef float f32x4 __attribute__((ext_vector_type(4)));
typedef unsigned short u16;
typedef unsigned int u32;
typedef u16 u16x4 __attribute__((ext_vector_type(4)));

#define TOKENS 16384
#define MROWS  65536

__device__ __forceinline__ u16 f2bf(float f) {
  union { __hip_bfloat16 h; u16 u; } c;
  c.h = __float2bfloat16(f);
  return c.u;
}
__device__ __forceinline__ float bf2f(u16 u) {
  union { u16 u; __hip_bfloat16 h; } c;
  c.u = u;
  return __bfloat162float(c.h);
}
// sigmoid-form gelu (validated r6-r9, absmax 6.1e-5)
__device__ __forceinline__ float gelu_f(float u) {
  float y2 = u * fmaf(0.07135481283f, u * u, 1.595769122f);
  float e = __expf(-y2);
  return u / (1.f + e);
}
// async global->LDS, 16B per lane; LDS dest is wave-uniform base + lane*16
__device__ __forceinline__ void gload16(const void* g, void* l) {
  __builtin_amdgcn_global_load_lds(
      (const __attribute__((address_space(1))) void*)g,
      (__attribute__((address_space(3))) void*)l, 16, 0, 0);
}

// ---------------- prep kernels ----------------
__global__ void kprep_G(const float* __restrict__ Wq, const float* __restrict__ Wk,
                        float* __restrict__ G) {
  int id = blockIdx.x * 256 + threadIdx.x;  // 16384
  int c = id >> 7, c2 = id & 127;
  const float4* a = (const float4*)(Wq + (size_t)c * 512);
  const float4* b = (const float4*)(Wk + (size_t)c2 * 512);
  float s = 0.f;
#pragma unroll 8
  for (int i = 0; i < 128; ++i) {
    float4 xa = a[i], yb = b[i];
    s += xa.x * yb.x + xa.y * yb.y + xa.z * yb.z + xa.w * yb.w;
  }
  G[id] = s * 0.044194173824159216f;
}

__global__ void kprep_Wvp(const float* __restrict__ Wv, const float* __restrict__ Wp,
                          u16* __restrict__ WvpT) {
  int id = blockIdx.x * 256 + threadIdx.x;  // 65536 : e*128+c
  int e = id >> 7, c = id & 127;
  float s = 0.f;
#pragma unroll 4
  for (int d = 0; d < 512; ++d) s += Wv[(size_t)c * 512 + d] * Wp[(size_t)d * 512 + e];
  WvpT[id] = f2bf(s);
}

__global__ void kprep_W1T(const float* __restrict__ W1, u16* __restrict__ W1T) {
  int id = blockIdx.x * 256 + threadIdx.x;  // 1M : f*512+e
  int f = id >> 9, e = id & 511;
  W1T[id] = f2bf(W1[(size_t)e * 2048 + f]);
}
// W2T with the H column permutation applied per 128-block (matches kff1's H store):
// stored slot fs holds true f_inner = (fs>>6)*64 + (fs&3)*16 + ((fs>>2)&15)
__global__ void kprep_W2T(const float* __restrict__ W2, u16* __restrict__ W2T) {
  int id = blockIdx.x * 256 + threadIdx.x;  // 1M : e*2048 + f_stored
  int e = id >> 11, fst = id & 2047;
  int fb = fst >> 7, fs = fst & 127;
  int f_true = fb * 128 + ((fs >> 6) << 6) + ((fs & 3) << 4) + ((fs >> 2) & 15);
  W2T[id] = f2bf(W2[(size_t)f_true * 512 + e]);
}

// ---------------- token attention: Z = softmax(mask(S G S^T)) S ----------------
__global__ __launch_bounds__(256) void ktoken(const float* __restrict__ x,
                                              const float* __restrict__ G,
                                              u16* __restrict__ Z) {
  __shared__ float Ss[4 * 512];
  __shared__ float T1s[4 * 512];
  __shared__ float Ws[4 * 16];
  int tid = threadIdx.x;
  int wave = tid >> 6, lane = tid & 63;
  int tok0 = blockIdx.x * 4;
  {
    const float4* xsrc = (const float4*)(x + (size_t)tok0 * 512);
    float4* sdst = (float4*)Ss;
    sdst[tid] = xsrc[tid];
    sdst[256 + tid] = xsrc[256 + tid];
  }
  __syncthreads();
  {
    const float* Sw = Ss + wave * 512;
    float a00 = 0, a01 = 0, a10 = 0, a11 = 0, a20 = 0, a21 = 0, a30 = 0, a31 = 0;
#pragma unroll 4
    for (int c = 0; c < 128; ++c) {
      float2 gg = ((const float2*)(G + (size_t)c * 128))[lane];
      float s0 = Sw[c], s1 = Sw[128 + c], s2 = Sw[256 + c], s3 = Sw[384 + c];
      a00 += s0 * gg.x; a01 += s0 * gg.y;
      a10 += s1 * gg.x; a11 += s1 * gg.y;
      a20 += s2 * gg.x; a21 += s2 * gg.y;
      a30 += s3 * gg.x; a31 += s3 * gg.y;
    }
    float* Tw = T1s + wave * 512;
    int c2 = lane * 2;
    Tw[c2] = a00; Tw[c2 + 1] = a01;
    Tw[128 + c2] = a10; Tw[128 + c2 + 1] = a11;
    Tw[256 + c2] = a20; Tw[256 + c2 + 1] = a21;
    Tw[384 + c2] = a30; Tw[384 + c2 + 1] = a31;
  }
  __syncthreads();
  if (lane < 16) {
    int i = lane >> 2, j = lane & 3;
    const float* Tw = T1s + wave * 512 + i * 128;
    const float* Sw = Ss + wave * 512 + j * 128;
    float d = 0.f;
#pragma unroll 8
    for (int c = 0; c < 128; ++c) d += Tw[c] * Sw[c];
    Ws[wave * 16 + i * 4 + j] = d;
  }
  __syncthreads();
  {
    float p[4][4];
    const float* ww = Ws + wave * 16;
#pragma unroll
    for (int i = 0; i < 4; ++i) {
      float m = -1e30f;
      for (int j = 0; j <= i; ++j) m = fmaxf(m, ww[i * 4 + j]);
      float s = 0.f;
      for (int j = 0; j <= i; ++j) { p[i][j] = __expf(ww[i * 4 + j] - m); s += p[i][j]; }
      float inv = 1.f / s;
      for (int j = 0; j <= i; ++j) p[i][j] *= inv;
      for (int j = i + 1; j < 4; ++j) p[i][j] = 0.f;
    }
    const float* Sw = Ss + wave * 512;
    int c = lane * 2;
    u32* zout = (u32*)(Z + (size_t)(tok0 + wave) * 512);
#pragma unroll
    for (int i = 0; i < 4; ++i) {
      float z0 = 0.f, z1 = 0.f;
#pragma unroll
      for (int j = 0; j < 4; ++j) {
        z0 += p[i][j] * Sw[j * 128 + c];
        z1 += p[i][j] * Sw[j * 128 + c + 1];
      }
      zout[i * 64 + lane] = (u32)f2bf(z0) | ((u32)f2bf(z1) << 16);
    }
  }
}

// ---------------- attn-out projection + bias + residual + LN1 -> X1 (bf16) ----------------
__global__ __launch_bounds__(512) void kattn(const u16* __restrict__ Z,
                                             const u16* __restrict__ WvpT,
                                             const float* __restrict__ bp,
                                             const float* __restrict__ x,
                                             const float* __restrict__ g1,
                                             const float* __restrict__ bln1,
                                             u16* __restrict__ X1) {
  __shared__ u16 AO[32768];
  __shared__ float rsum[64 * 4];
  __shared__ float rsq[64 * 4];
  __shared__ float mus[64];
  __shared__ float rss[64];
  char* smem = (char*)AO;
  int tid = threadIdx.x;
  int lane = tid & 63, wid = tid >> 6;
  int wm = wid >> 2, wnq = wid & 3;
  int lane_lo = lane & 15, lane_hi = lane >> 4;
  int m0 = blockIdx.x * 64;
  {
    const bf16x8* src = (const bf16x8*)(Z + (size_t)m0 * 128);
#pragma unroll
    for (int it = 0; it < 2; ++it) {
      int idx8 = it * 512 + tid;
      int row = idx8 >> 4;
      int byte = (idx8 * 16) ^ ((row & 7) << 4);
      *(bf16x8*)(smem + byte) = src[idx8];
    }
  }
  __syncthreads();
  f32x4 acc[2][8];
#pragma unroll
  for (int mi = 0; mi < 2; ++mi)
#pragma unroll
    for (int ni = 0; ni < 8; ++ni) acc[mi][ni] = (f32x4){0.f, 0.f, 0.f, 0.f};
#pragma unroll
  for (int ks = 0; ks < 4; ++ks) {
    bf16x8 af[2];
#pragma unroll
    for (int mi = 0; mi < 2; ++mi) {
      int row = wm * 32 + mi * 16 + lane_lo;
      int byte = (row * 256 + (ks * 32 + lane_hi * 8) * 2) ^ ((row & 7) << 4);
      af[mi] = *(const bf16x8*)(smem + byte);
    }
#pragma unroll
    for (int ni = 0; ni < 8; ++ni) {
      int n = wnq * 128 + ni * 16 + lane_lo;
      bf16x8 bfr = *(const bf16x8*)(WvpT + (size_t)n * 128 + ks * 32 + lane_hi * 8);
#pragma unroll
      for (int mi = 0; mi < 2; ++mi)
        acc[mi][ni] = __builtin_amdgcn_mfma_f32_16x16x32_bf16(af[mi], bfr, acc[mi][ni], 0, 0, 0);
    }
  }
#pragma unroll
  for (int mi = 0; mi < 2; ++mi) {
#pragma unroll
    for (int j = 0; j < 4; ++j) {
      int rl = wm * 32 + mi * 16 + lane_hi * 4 + j;
      int R = m0 + rl;
      const float* xrow = x + (size_t)(R >> 2) * 512;
      float s = 0.f, q = 0.f;
#pragma unroll
      for (int ni = 0; ni < 8; ++ni) {
        int col = wnq * 128 + ni * 16 + lane_lo;
        float val = acc[mi][ni][j] + bp[col] + xrow[col];
        acc[mi][ni][j] = val;
        s += val; q += val * val;
      }
#pragma unroll
      for (int off = 1; off < 16; off <<= 1) { s += __shfl_xor(s, off); q += __shfl_xor(q, off); }
      if (lane_lo == 0) { rsum[rl * 4 + wnq] = s; rsq[rl * 4 + wnq] = q; }
    }
  }
  __syncthreads();
  if (tid < 64) {
    float s = rsum[tid * 4] + rsum[tid * 4 + 1] + rsum[tid * 4 + 2] + rsum[tid * 4 + 3];
    float q = rsq[tid * 4] + rsq[tid * 4 + 1] + rsq[tid * 4 + 2] + rsq[tid * 4 + 3];
    float mu = s * (1.f / 512.f);
    float var = q * (1.f / 512.f) - mu * mu;
    mus[tid] = mu;
    rss[tid] = rsqrtf(var + 512.0f);
  }
  __syncthreads();
#pragma unroll
  for (int mi = 0; mi < 2; ++mi) {
#pragma unroll
    for (int j = 0; j < 4; ++j) {
      int rl = wm * 32 + mi * 16 + lane_hi * 4 + j;
      float mu = mus[rl], rs = rss[rl];
#pragma unroll
      for (int ni = 0; ni < 8; ++ni) {
        int col = wnq * 128 + ni * 16 + lane_lo;
        AO[rl * 512 + col] = f2bf((acc[mi][ni][j] - mu) * rs * g1[col] + bln1[col]);
      }
    }
  }
  __syncthreads();
  {
    bf16x8* dst = (bf16x8*)(X1 + (size_t)m0 * 512);
    const bf16x8* s8 = (const bf16x8*)AO;
#pragma unroll
    for (int it = 0; it < 8; ++it) dst[it * 512 + tid] = s8[it * 512 + tid];
  }
}

// ========== kff1 v2: resident-B (W1T nb-panel, 128KB LDS) + streamed A ==========
// 512 threads, 8 waves as 4M x 2N; wave tile 32x64; block tile 128x128.
// LDS: Bres 8 panels [128][64] (128KB, staged once) + Abuf 2 slots [128][64]
// (32KB) = exactly 160KB -> 1 block/CU. Block owns (nb, 1024-row strip), loops
// 8 m-tiles x 8 K-steps with counted A-prefetch: gate vmcnt(2), never 0
// mid-loop; slot WAR barrier-protected. Epilogue geometry matches r7's kff1 so
// the H permutation / kprep_W2T are unchanged (validated r7-r9).
__global__ __launch_bounds__(512) void kff1(const u16* __restrict__ X1s,
                                            const u16* __restrict__ W1T,
                                            const float* __restrict__ b1v,
                                            u16* __restrict__ H) {
  __shared__ __align__(16) u16 Bres[8 * 8192];   // 128KB
  __shared__ __align__(16) u16 Abuf[2 * 8192];   // 32KB
  char* BresC = (char*)Bres;
  char* AbufC = (char*)Abuf;
  int tid = threadIdx.x, lane = tid & 63, wid = tid >> 6;
  int lane_lo = lane & 15, lane_hi = lane >> 4;
  int wm = wid >> 1, wn = wid & 1;
  int rl8 = lane >> 3, u8 = lane & 7;
  int bid = blockIdx.x;
  // grid = strips*16; XCD-group strips when strips%8==0 (16 nb of a strip -> same XCD)
  int strip, nb;
  if ((gridDim.x & 127) == 0) {
    int spx = gridDim.x >> 7;          // strips per XCD
    int xcd = bid & 7, idx = bid >> 3;
    strip = xcd * spx + (idx >> 4);
    nb = idx & 15;
  } else {
    strip = bid >> 4;
    nb = bid & 15;
  }
  const u16* Ap = X1s + (size_t)strip * 1024 * 512;
  const u16* Bp = W1T + (size_t)nb * 128 * 512;

  // stage resident B: 8 K-panels, each wave stages its 16 rows (2 insts)
#pragma unroll
  for (int kp = 0; kp < 8; ++kp) {
#pragma unroll
    for (int i = 0; i < 2; ++i) {
      int row = wid * 16 + i * 8 + rl8;
      int usw = u8 ^ (row & 7);
      gload16(Bp + (size_t)row * 512 + kp * 64 + usw * 8,
              BresC + kp * 16384 + wid * 2048 + i * 1024);
    }
  }
  // streamed A: panel t = mb*8 + k -> slot t&1
  auto stageA = [&](int t) {
    int mb = t >> 3, k = t & 7;
    char* dst = AbufC + (t & 1) * 16384 + wid * 2048;
#pragma unroll
    for (int i = 0; i < 2; ++i) {
      int row = wid * 16 + i * 8 + rl8;
      int usw = u8 ^ (row & 7);
      gload16(Ap + (size_t)(mb * 128 + row) * 512 + k * 64 + usw * 8,
              dst + i * 1024);
    }
  };
  stageA(0);
  stageA(1);

  f32x4 acc[2][4];
#pragma unroll
  for (int mi = 0; mi < 2; ++mi)
#pragma unroll
    for (int ni = 0; ni < 4; ++ni) acc[mi][ni] = (f32x4){0.f, 0.f, 0.f, 0.f};
  float bvals[4];
#pragma unroll
  for (int ni = 0; ni < 4; ++ni) bvals[ni] = b1v[nb * 128 + wn * 64 + ni * 16 + lane_lo];
  const int colb = nb * 128 + (wn * 16 + lane_lo) * 4;

  const int T = 64;  // 8 m-tiles x 8 K-steps
  for (int t = 0; t < T; ++t) {
    int k = t & 7, mb = t >> 3;
    // gate: A(t) (and B at t=0) landed; A(t+1) stays in flight
    if (t < T - 1) asm volatile("s_waitcnt vmcnt(2)" ::: "memory");
    else           asm volatile("s_waitcnt vmcnt(0)" ::: "memory");
    __builtin_amdgcn_sched_barrier(0);
    __builtin_amdgcn_s_barrier();
    __builtin_amdgcn_sched_barrier(0);
    {
      char* Ab = AbufC + (t & 1) * 16384;
      char* Bb = BresC + k * 16384;
#pragma unroll
      for (int ks = 0; ks < 2; ++ks) {
        bf16x8 av[2], bv[4];
#pragma unroll
        for (int mi = 0; mi < 2; ++mi) {
          int row = wm * 32 + mi * 16 + lane_lo;
          int usw = (ks * 4 + lane_hi) ^ (row & 7);
          av[mi] = *(const bf16x8*)(Ab + row * 128 + usw * 16);
        }
#pragma unroll
        for (int ni = 0; ni < 4; ++ni) {
          int row = wn * 64 + ni * 16 + lane_lo;
          int usw = (ks * 4 + lane_hi) ^ (row & 7);
          bv[ni] = *(const bf16x8*)(Bb + row * 128 + usw * 16);
        }
#pragma unroll
        for (int mi = 0; mi < 2; ++mi)
#pragma unroll
          for (int ni = 0; ni < 4; ++ni)
            acc[mi][ni] = __builtin_amdgcn_mfma_f32_16x16x32_bf16(av[mi], bv[ni], acc[mi][ni], 0, 0, 0);
      }
    }
    __builtin_amdgcn_sched_barrier(0);
    __builtin_amdgcn_s_barrier();   // all waves' reads of slot t&1 done
    __builtin_amdgcn_sched_barrier(0);
    if (t + 2 < T) stageA(t + 2);   // -> slot t&1, just freed
    if (k == 7) {
      // epilogue for m-tile mb (prefetch of next tile stays in flight above this)
      size_t rowbase = (size_t)strip * 1024 + (size_t)mb * 128;
#pragma unroll
      for (int mi = 0; mi < 2; ++mi)
#pragma unroll
        for (int j = 0; j < 4; ++j) {
          int rl = wm * 32 + mi * 16 + lane_hi * 4 + j;
          u16x4 pk;
#pragma unroll
          for (int ni = 0; ni < 4; ++ni)
            pk[ni] = f2bf(gelu_f(acc[mi][ni][j] + bvals[ni]));
          *(u16x4*)(H + (rowbase + rl) * 2048 + colb) = pk;
        }
#pragma unroll
      for (int mi = 0; mi < 2; ++mi)
#pragma unroll
        for (int ni = 0; ni < 4; ++ni) acc[mi][ni] = (f32x4){0.f, 0.f, 0.f, 0.f};
    }
  }
}

// ====== kff2 GEMM core: counted-vmcnt asymmetric pipeline (A 3-buf, B 2-buf) ======
// (r9 core; at S=4 the A side = H slice is L3-resident so prefetch depth is cheap)
template<int KDIM>
__device__ __forceinline__ void gemm_core(const u16* __restrict__ Ap,
                                          const u16* __restrict__ Bp,
                                          u16* AbBase, u16* BbBase,
                                          int wid, int lane, f32x4 acc[4][4]) {
  const int lane_lo = lane & 15, lane_hi = lane >> 4;
  const int wm = wid >> 1, wn = wid & 1;
  const int rl8 = lane >> 3, u8 = lane & 7;
  constexpr int NK = KDIM / 64;
  char* AbC = (char*)AbBase;
  char* BbC = (char*)BbBase;

  auto stageA = [&](int k) {
    char* dst = AbC + (k % 3) * 16384 + wid * 4096;
    int k0 = k * 64;
#pragma unroll
    for (int i = 0; i < 4; ++i) {
      int row = wid * 32 + i * 8 + rl8;
      int usw = u8 ^ (row & 7);
      gload16(Ap + (size_t)row * KDIM + k0 + usw * 8, dst + i * 1024);
    }
  };
  auto stageB = [&](int k) {
    char* dst = BbC + (k % 2) * 16384 + wid * 4096;
    int k0 = k * 64;
#pragma unroll
    for (int i = 0; i < 4; ++i) {
      int row = wid * 32 + i * 8 + rl8;
      int usw = u8 ^ (row & 7);
      gload16(Bp + (size_t)row * KDIM + k0 + usw * 8, dst + i * 1024);
    }
  };
  auto compute = [&](int k) {
    char* Ab = AbC + (k % 3) * 16384;
    char* Bb = BbC + (k % 2) * 16384;
#pragma unroll
    for (int ks = 0; ks < 2; ++ks) {
      bf16x8 av[4], bv[4];
#pragma unroll
      for (int mi = 0; mi < 4; ++mi) {
        int row = wm * 64 + mi * 16 + lane_lo;
        int usw = (ks * 4 + lane_hi) ^ (row & 7);
        av[mi] = *(const bf16x8*)(Ab + row * 128 + usw * 16);
      }
#pragma unroll
      for (int ni = 0; ni < 4; ++ni) {
        int row = wn * 64 + ni * 16 + lane_lo;
        int usw = (ks * 4 + lane_hi) ^ (row & 7);
        bv[ni] = *(const bf16x8*)(Bb + row * 128 + usw * 16);
      }
#pragma unroll
      for (int mi = 0; mi < 4; ++mi)
#pragma unroll
        for (int ni = 0; ni < 4; ++ni)
          acc[mi][ni] = __builtin_amdgcn_mfma_f32_16x16x32_bf16(av[mi], bv[ni], acc[mi][ni], 0, 0, 0);
    }
  };

  stageA(0); stageB(0); stageA(1); stageB(1); stageA(2);
  for (int k = 0; k < NK; ++k) {
    if (k < NK - 2)       asm volatile("s_waitcnt vmcnt(12)" ::: "memory");
    else if (k == NK - 2) asm volatile("s_waitcnt vmcnt(8)" ::: "memory");
    else                  asm volatile("s_waitcnt vmcnt(0)" ::: "memory");
    __builtin_amdgcn_sched_barrier(0);
    __builtin_amdgcn_s_barrier();
    __builtin_amdgcn_sched_barrier(0);
    compute(k);
    __builtin_amdgcn_sched_barrier(0);
    __builtin_amdgcn_s_barrier();
    __builtin_amdgcn_sched_barrier(0);
    if (k + 2 < NK) stageB(k + 2);
    if (k + 3 < NK) stageA(k + 3);
  }
}

// FF2: P = H @ W2 + b2 + X1 (pre-LN, f32), K=2048, N=512 (4 n-blocks)
__global__ __launch_bounds__(256) void kff2(const u16* __restrict__ H,
                                            const u16* __restrict__ W2T,
                                            const float* __restrict__ b2v,
                                            const u16* __restrict__ X1s,
                                            float* __restrict__ Ps) {
  __shared__ __align__(16) u16 Ab[3 * 8192];
  __shared__ __align__(16) u16 Bb[2 * 8192];
  int tid = threadIdx.x, lane = tid & 63, wid = tid >> 6;
  int nwg = gridDim.x, bid = blockIdx.x;
  int m128 = nwg >> 2;
  int xcd = bid & 7, idx = bid >> 3;
  int mb = xcd * (m128 >> 3) + (idx >> 2);
  int nb = idx & 3;
  const u16* Ap = H + (size_t)mb * 128 * 2048;
  const u16* Bp = W2T + (size_t)nb * 128 * 2048;
  f32x4 acc[4][4];
#pragma unroll
  for (int mi = 0; mi < 4; ++mi)
#pragma unroll
    for (int ni = 0; ni < 4; ++ni) acc[mi][ni] = (f32x4){0.f, 0.f, 0.f, 0.f};
  gemm_core<2048>(Ap, Bp, Ab, Bb, wid, lane, acc);
  int lane_lo = lane & 15, lane_hi = lane >> 4;
  int wm = wid >> 1, wn = wid & 1;
#pragma unroll
  for (int mi = 0; mi < 4; ++mi)
#pragma unroll
    for (int j = 0; j < 4; ++j) {
      int rl = wm * 64 + mi * 16 + lane_hi * 4 + j;
      size_t row = (size_t)mb * 128 + rl;
      const u16* xrow = X1s + row * 512 + nb * 128;
      float* prow = Ps + row * 512 + nb * 128;
#pragma unroll
      for (int ni = 0; ni < 4; ++ni) {
        int col = wn * 64 + ni * 16 + lane_lo;
        prow[col] = acc[mi][ni][j] + b2v[nb * 128 + col] + bf2f(xrow[col]);
      }
    }
}

// LN2 in-place over rows of P (= out): one wave per row
__global__ __launch_bounds__(512) void kln2(float* __restrict__ P,
                                            const float* __restrict__ g2,
                                            const float* __restrict__ bb2) {
  int wid = threadIdx.x >> 6, lane = threadIdx.x & 63;
  size_t row = (size_t)blockIdx.x * 8 + wid;
  float* pr = P + row * 512;
  float4 v0 = *(float4*)(pr + lane * 4);
  float4 v1 = *(float4*)(pr + 256 + lane * 4);
  float s = v0.x + v0.y + v0.z + v0.w + v1.x + v1.y + v1.z + v1.w;
  float q = v0.x * v0.x + v0.y * v0.y + v0.z * v0.z + v0.w * v0.w +
            v1.x * v1.x + v1.y * v1.y + v1.z * v1.z + v1.w * v1.w;
#pragma unroll
  for (int off = 1; off < 64; off <<= 1) { s += __shfl_xor(s, off); q += __shfl_xor(q, off); }
  float mu = s * (1.f / 512.f);
  float rs = rsqrtf(q * (1.f / 512.f) - mu * mu + 512.0f);
  float4 ga = *(const float4*)(g2 + lane * 4);
  float4 gb = *(const float4*)(g2 + 256 + lane * 4);
  float4 ba = *(const float4*)(bb2 + lane * 4);
  float4 bb = *(const float4*)(bb2 + 256 + lane * 4);
  v0.x = (v0.x - mu) * rs * ga.x + ba.x;
  v0.y = (v0.y - mu) * rs * ga.y + ba.y;
  v0.z = (v0.z - mu) * rs * ga.z + ba.z;
  v0.w = (v0.w - mu) * rs * ga.w + ba.w;
  v1.x = (v1.x - mu) * rs * gb.x + bb.x;
  v1.y = (v1.y - mu) * rs * gb.y + bb.y;
  v1.z = (v1.z - mu) * rs * gb.z + bb.z;
  v1.w = (v1.w - mu) * rs * gb.w + bb.w;
  *(float4*)(pr + lane * 4) = v0;
  *(float4*)(pr + 256 + lane * 4) = v1;
}

extern "C" void kernel_launch(void* const* d_in, const int* in_sizes, int n_in,
                              void* d_out, int out_size, void* d_ws, size_t ws_size,
                              hipStream_t stream) {
  const float* x   = (const float*)d_in[0];
  const float* Wq  = (const float*)d_in[1];
  const float* Wk  = (const float*)d_in[2];
  const float* Wv  = (const float*)d_in[3];
  const float* Wp  = (const float*)d_in[4];
  const float* bp  = (const float*)d_in[5];
  const float* W1  = (const float*)d_in[6];
  const float* b1  = (const float*)d_in[7];
  const float* W2  = (const float*)d_in[8];
  const float* b2  = (const float*)d_in[9];
  const float* g1  = (const float*)d_in[10];
  const float* bb1 = (const float*)d_in[11];
  const float* g2  = (const float*)d_in[12];
  const float* bb2 = (const float*)d_in[13];
  float* out = (float*)d_out;

  char* ws = (char*)d_ws;
  float* G  = (float*)ws;                    // 64KB region (256KB reserved)
  u16* WvpT = (u16*)(ws + (256 << 10));      // 128KB
  u16* W1T  = (u16*)(ws + (1 << 20));        // 2MB
  u16* W2T  = (u16*)(ws + (3 << 20));        // 2MB
  u16* Z    = (u16*)(ws + (5 << 20));        // 16MB
  u16* X1   = (u16*)(ws + (21 << 20));       // 64MB
  u16* H    = (u16*)(ws + (85ull << 20));    // H slice region

  hipLaunchKernelGGL(kprep_G,   dim3(64),   dim3(256), 0, stream, Wq, Wk, G);
  hipLaunchKernelGGL(kprep_Wvp, dim3(256),  dim3(256), 0, stream, Wv, Wp, WvpT);
  hipLaunchKernelGGL(kprep_W1T, dim3(4096), dim3(256), 0, stream, W1, W1T);
  hipLaunchKernelGGL(kprep_W2T, dim3(4096), dim3(256), 0, stream, W2, W2T);
  hipLaunchKernelGGL(ktoken,    dim3(4096), dim3(256), 0, stream, x, G, Z);
  hipLaunchKernelGGL(kattn,     dim3(1024), dim3(512), 0, stream, Z, WvpT, bp, x, g1, bb1, X1);

  // S>=4 so each H slice (<=64MB) is L3-resident between kff1 and kff2
  const size_t hbase = 85ull << 20;
  int S = 64;
  for (int c = 4; c <= 64; c <<= 1) {
    if (hbase + (268435456ull / (size_t)c) <= ws_size) { S = c; break; }
  }
  int Ms = MROWS / S;          // 16384 at S=4
  int strips = Ms / 1024;      // 1024-row strips for kff1 v2
  for (int s = 0; s < S; ++s) {
    const u16* x1s = X1 + (size_t)s * Ms * 512;
    float* outs = out + (size_t)s * Ms * 512;
    hipLaunchKernelGGL(kff1, dim3(strips * 16),    dim3(512), 0, stream, x1s, W1T, b1, H);
    hipLaunchKernelGGL(kff2, dim3((Ms / 128) * 4), dim3(256), 0, stream, H, W2T, b2, x1s, outs);
  }
  hipLaunchKernelGGL(kln2, dim3(8192), dim3(512), 0, stream, out, g2, bb2);
}

// Round 11
// 676.449 us; speedup vs baseline: 1.1516x; 1.1516x over previous
//
#include <hip/hip_runtime.h>
#include <hip/hip_bf16.h>
#include <math.h>

typedef __bf16 bf16x8 __attribute__((ext_vector_type(8)));
typedef float f32x4 __attribute__((ext_vector_type(4)));
typedef unsigned short u16;
typedef unsigned int u32;
typedef u16 u16x4 __attribute__((ext_vector_type(4)));

#define TOKENS 16384
#define MROWS  65536

__device__ __forceinline__ u16 f2bf(float f) {
  union { __hip_bfloat16 h; u16 u; } c;
  c.h = __float2bfloat16(f);
  return c.u;
}
__device__ __forceinline__ float bf2f(u16 u) {
  union { u16 u; __hip_bfloat16 h; } c;
  c.u = u;
  return __bfloat162float(c.h);
}
// sigmoid-form gelu (validated r6-r10, absmax 6.1e-5)
__device__ __forceinline__ float gelu_f(float u) {
  float y2 = u * fmaf(0.07135481283f, u * u, 1.595769122f);
  float e = __expf(-y2);
  return u / (1.f + e);
}
// async global->LDS, 16B per lane; LDS dest is wave-uniform base + lane*16
__device__ __forceinline__ void gload16(const void* g, void* l) {
  __builtin_amdgcn_global_load_lds(
      (const __attribute__((address_space(1))) void*)g,
      (__attribute__((address_space(3))) void*)l, 16, 0, 0);
}

// ---------------- prep kernels ----------------
__global__ void kprep_G(const float* __restrict__ Wq, const float* __restrict__ Wk,
                        float* __restrict__ G) {
  int id = blockIdx.x * 256 + threadIdx.x;  // 16384
  int c = id >> 7, c2 = id & 127;
  const float4* a = (const float4*)(Wq + (size_t)c * 512);
  const float4* b = (const float4*)(Wk + (size_t)c2 * 512);
  float s = 0.f;
#pragma unroll 8
  for (int i = 0; i < 128; ++i) {
    float4 xa = a[i], yb = b[i];
    s += xa.x * yb.x + xa.y * yb.y + xa.z * yb.z + xa.w * yb.w;
  }
  G[id] = s * 0.044194173824159216f;
}

__global__ void kprep_Wvp(const float* __restrict__ Wv, const float* __restrict__ Wp,
                          u16* __restrict__ WvpT) {
  int id = blockIdx.x * 256 + threadIdx.x;  // 65536 : e*128+c
  int e = id >> 7, c = id & 127;
  float s = 0.f;
#pragma unroll 4
  for (int d = 0; d < 512; ++d) s += Wv[(size_t)c * 512 + d] * Wp[(size_t)d * 512 + e];
  WvpT[id] = f2bf(s);
}

__global__ void kprep_W1T(const float* __restrict__ W1, u16* __restrict__ W1T) {
  int id = blockIdx.x * 256 + threadIdx.x;  // 1M : f*512+e
  int f = id >> 9, e = id & 511;
  W1T[id] = f2bf(W1[(size_t)e * 2048 + f]);
}
// W2T with the H column permutation applied per 128-block (matches kff1's H store):
// stored slot fs holds true f_inner = (fs>>6)*64 + (fs&3)*16 + ((fs>>2)&15)
__global__ void kprep_W2T(const float* __restrict__ W2, u16* __restrict__ W2T) {
  int id = blockIdx.x * 256 + threadIdx.x;  // 1M : e*2048 + f_stored
  int e = id >> 11, fst = id & 2047;
  int fb = fst >> 7, fs = fst & 127;
  int f_true = fb * 128 + ((fs >> 6) << 6) + ((fs & 3) << 4) + ((fs >> 2) & 15);
  W2T[id] = f2bf(W2[(size_t)f_true * 512 + e]);
}

// ---------------- token attention: Z = softmax(mask(S G S^T)) S ----------------
__global__ __launch_bounds__(256) void ktoken(const float* __restrict__ x,
                                              const float* __restrict__ G,
                                              u16* __restrict__ Z) {
  __shared__ float Ss[4 * 512];
  __shared__ float T1s[4 * 512];
  __shared__ float Ws[4 * 16];
  int tid = threadIdx.x;
  int wave = tid >> 6, lane = tid & 63;
  int tok0 = blockIdx.x * 4;
  {
    const float4* xsrc = (const float4*)(x + (size_t)tok0 * 512);
    float4* sdst = (float4*)Ss;
    sdst[tid] = xsrc[tid];
    sdst[256 + tid] = xsrc[256 + tid];
  }
  __syncthreads();
  {
    const float* Sw = Ss + wave * 512;
    float a00 = 0, a01 = 0, a10 = 0, a11 = 0, a20 = 0, a21 = 0, a30 = 0, a31 = 0;
#pragma unroll 4
    for (int c = 0; c < 128; ++c) {
      float2 gg = ((const float2*)(G + (size_t)c * 128))[lane];
      float s0 = Sw[c], s1 = Sw[128 + c], s2 = Sw[256 + c], s3 = Sw[384 + c];
      a00 += s0 * gg.x; a01 += s0 * gg.y;
      a10 += s1 * gg.x; a11 += s1 * gg.y;
      a20 += s2 * gg.x; a21 += s2 * gg.y;
      a30 += s3 * gg.x; a31 += s3 * gg.y;
    }
    float* Tw = T1s + wave * 512;
    int c2 = lane * 2;
    Tw[c2] = a00; Tw[c2 + 1] = a01;
    Tw[128 + c2] = a10; Tw[128 + c2 + 1] = a11;
    Tw[256 + c2] = a20; Tw[256 + c2 + 1] = a21;
    Tw[384 + c2] = a30; Tw[384 + c2 + 1] = a31;
  }
  __syncthreads();
  if (lane < 16) {
    int i = lane >> 2, j = lane & 3;
    const float* Tw = T1s + wave * 512 + i * 128;
    const float* Sw = Ss + wave * 512 + j * 128;
    float d = 0.f;
#pragma unroll 8
    for (int c = 0; c < 128; ++c) d += Tw[c] * Sw[c];
    Ws[wave * 16 + i * 4 + j] = d;
  }
  __syncthreads();
  {
    float p[4][4];
    const float* ww = Ws + wave * 16;
#pragma unroll
    for (int i = 0; i < 4; ++i) {
      float m = -1e30f;
      for (int j = 0; j <= i; ++j) m = fmaxf(m, ww[i * 4 + j]);
      float s = 0.f;
      for (int j = 0; j <= i; ++j) { p[i][j] = __expf(ww[i * 4 + j] - m); s += p[i][j]; }
      float inv = 1.f / s;
      for (int j = 0; j <= i; ++j) p[i][j] *= inv;
      for (int j = i + 1; j < 4; ++j) p[i][j] = 0.f;
    }
    const float* Sw = Ss + wave * 512;
    int c = lane * 2;
    u32* zout = (u32*)(Z + (size_t)(tok0 + wave) * 512);
#pragma unroll
    for (int i = 0; i < 4; ++i) {
      float z0 = 0.f, z1 = 0.f;
#pragma unroll
      for (int j = 0; j < 4; ++j) {
        z0 += p[i][j] * Sw[j * 128 + c];
        z1 += p[i][j] * Sw[j * 128 + c + 1];
      }
      zout[i * 64 + lane] = (u32)f2bf(z0) | ((u32)f2bf(z1) << 16);
    }
  }
}

// ---------------- attn-out projection + bias + residual + LN1 -> X1 (bf16) ----------------
__global__ __launch_bounds__(512) void kattn(const u16* __restrict__ Z,
                                             const u16* __restrict__ WvpT,
                                             const float* __restrict__ bp,
                                             const float* __restrict__ x,
                                             const float* __restrict__ g1,
                                             const float* __restrict__ bln1,
                                             u16* __restrict__ X1) {
  __shared__ u16 AO[32768];
  __shared__ float rsum[64 * 4];
  __shared__ float rsq[64 * 4];
  __shared__ float mus[64];
  __shared__ float rss[64];
  char* smem = (char*)AO;
  int tid = threadIdx.x;
  int lane = tid & 63, wid = tid >> 6;
  int wm = wid >> 2, wnq = wid & 3;
  int lane_lo = lane & 15, lane_hi = lane >> 4;
  int m0 = blockIdx.x * 64;
  {
    const bf16x8* src = (const bf16x8*)(Z + (size_t)m0 * 128);
#pragma unroll
    for (int it = 0; it < 2; ++it) {
      int idx8 = it * 512 + tid;
      int row = idx8 >> 4;
      int byte = (idx8 * 16) ^ ((row & 7) << 4);
      *(bf16x8*)(smem + byte) = src[idx8];
    }
  }
  __syncthreads();
  f32x4 acc[2][8];
#pragma unroll
  for (int mi = 0; mi < 2; ++mi)
#pragma unroll
    for (int ni = 0; ni < 8; ++ni) acc[mi][ni] = (f32x4){0.f, 0.f, 0.f, 0.f};
#pragma unroll
  for (int ks = 0; ks < 4; ++ks) {
    bf16x8 af[2];
#pragma unroll
    for (int mi = 0; mi < 2; ++mi) {
      int row = wm * 32 + mi * 16 + lane_lo;
      int byte = (row * 256 + (ks * 32 + lane_hi * 8) * 2) ^ ((row & 7) << 4);
      af[mi] = *(const bf16x8*)(smem + byte);
    }
#pragma unroll
    for (int ni = 0; ni < 8; ++ni) {
      int n = wnq * 128 + ni * 16 + lane_lo;
      bf16x8 bfr = *(const bf16x8*)(WvpT + (size_t)n * 128 + ks * 32 + lane_hi * 8);
#pragma unroll
      for (int mi = 0; mi < 2; ++mi)
        acc[mi][ni] = __builtin_amdgcn_mfma_f32_16x16x32_bf16(af[mi], bfr, acc[mi][ni], 0, 0, 0);
    }
  }
#pragma unroll
  for (int mi = 0; mi < 2; ++mi) {
#pragma unroll
    for (int j = 0; j < 4; ++j) {
      int rl = wm * 32 + mi * 16 + lane_hi * 4 + j;
      int R = m0 + rl;
      const float* xrow = x + (size_t)(R >> 2) * 512;
      float s = 0.f, q = 0.f;
#pragma unroll
      for (int ni = 0; ni < 8; ++ni) {
        int col = wnq * 128 + ni * 16 + lane_lo;
        float val = acc[mi][ni][j] + bp[col] + xrow[col];
        acc[mi][ni][j] = val;
        s += val; q += val * val;
      }
#pragma unroll
      for (int off = 1; off < 16; off <<= 1) { s += __shfl_xor(s, off); q += __shfl_xor(q, off); }
      if (lane_lo == 0) { rsum[rl * 4 + wnq] = s; rsq[rl * 4 + wnq] = q; }
    }
  }
  __syncthreads();
  if (tid < 64) {
    float s = rsum[tid * 4] + rsum[tid * 4 + 1] + rsum[tid * 4 + 2] + rsum[tid * 4 + 3];
    float q = rsq[tid * 4] + rsq[tid * 4 + 1] + rsq[tid * 4 + 2] + rsq[tid * 4 + 3];
    float mu = s * (1.f / 512.f);
    float var = q * (1.f / 512.f) - mu * mu;
    mus[tid] = mu;
    rss[tid] = rsqrtf(var + 512.0f);
  }
  __syncthreads();
#pragma unroll
  for (int mi = 0; mi < 2; ++mi) {
#pragma unroll
    for (int j = 0; j < 4; ++j) {
      int rl = wm * 32 + mi * 16 + lane_hi * 4 + j;
      float mu = mus[rl], rs = rss[rl];
#pragma unroll
      for (int ni = 0; ni < 8; ++ni) {
        int col = wnq * 128 + ni * 16 + lane_lo;
        AO[rl * 512 + col] = f2bf((acc[mi][ni][j] - mu) * rs * g1[col] + bln1[col]);
      }
    }
  }
  __syncthreads();
  {
    bf16x8* dst = (bf16x8*)(X1 + (size_t)m0 * 512);
    const bf16x8* s8 = (const bf16x8*)AO;
#pragma unroll
    for (int it = 0; it < 8; ++it) dst[it * 512 + tid] = s8[it * 512 + tid];
  }
}

// ======== single-buffered m97-style GEMM core (r7: best for short-K kff1) ========
// 128x128 tile, BK=64; LDS 32KB; 2 barriers/K-step; both-sides XOR swizzle.
template<int KDIM>
__device__ __forceinline__ void gemm_core_sb(const u16* __restrict__ Ap,
                                             const u16* __restrict__ Bp,
                                             u16* Ab, u16* Bb,
                                             int wid, int lane, f32x4 acc[4][4]) {
  const int lane_lo = lane & 15, lane_hi = lane >> 4;
  const int wm = wid >> 1, wn = wid & 1;
  const int rl8 = lane >> 3, u8 = lane & 7;
  char* AbC = (char*)Ab;
  char* BbC = (char*)Bb;
  for (int k0 = 0; k0 < KDIM; k0 += 64) {
#pragma unroll
    for (int i = 0; i < 4; ++i) {
      int row = wid * 32 + i * 8 + rl8;
      int usw = u8 ^ (row & 7);
      size_t goff = (size_t)row * KDIM + k0 + usw * 8;
      gload16(Ap + goff, AbC + wid * 4096 + i * 1024);
      gload16(Bp + goff, BbC + wid * 4096 + i * 1024);
    }
    __syncthreads();
#pragma unroll
    for (int ks = 0; ks < 2; ++ks) {
      bf16x8 av[4], bv[4];
#pragma unroll
      for (int mi = 0; mi < 4; ++mi) {
        int row = wm * 64 + mi * 16 + lane_lo;
        int usw = (ks * 4 + lane_hi) ^ (row & 7);
        av[mi] = *(const bf16x8*)(AbC + row * 128 + usw * 16);
      }
#pragma unroll
      for (int ni = 0; ni < 4; ++ni) {
        int row = wn * 64 + ni * 16 + lane_lo;
        int usw = (ks * 4 + lane_hi) ^ (row & 7);
        bv[ni] = *(const bf16x8*)(BbC + row * 128 + usw * 16);
      }
#pragma unroll
      for (int mi = 0; mi < 4; ++mi)
#pragma unroll
        for (int ni = 0; ni < 4; ++ni)
          acc[mi][ni] = __builtin_amdgcn_mfma_f32_16x16x32_bf16(av[mi], bv[ni], acc[mi][ni], 0, 0, 0);
    }
    __syncthreads();
  }
}

// ======== 2-phase double-buffered core (r8: best for long-K, H-streaming kff2) ========
// LDS 64KB; per K-step: stage(next) -> compute(cur) -> vmcnt(0) -> s_barrier.
template<int KDIM>
__device__ __forceinline__ void gemm_core_db(const u16* __restrict__ Ap,
                                             const u16* __restrict__ Bp,
                                             u16* AbBase, u16* BbBase,
                                             int wid, int lane, f32x4 acc[4][4]) {
  const int lane_lo = lane & 15, lane_hi = lane >> 4;
  const int wm = wid >> 1, wn = wid & 1;
  const int rl8 = lane >> 3, u8 = lane & 7;

  auto stage = [&](int buf, int k0) {
    char* AbC = (char*)AbBase + buf * 16384;
    char* BbC = (char*)BbBase + buf * 16384;
#pragma unroll
    for (int i = 0; i < 4; ++i) {
      int row = wid * 32 + i * 8 + rl8;
      int usw = u8 ^ (row & 7);
      size_t goff = (size_t)row * KDIM + k0 + usw * 8;
      gload16(Ap + goff, AbC + wid * 4096 + i * 1024);
      gload16(Bp + goff, BbC + wid * 4096 + i * 1024);
    }
  };
  auto compute = [&](int buf) {
    char* AbC = (char*)AbBase + buf * 16384;
    char* BbC = (char*)BbBase + buf * 16384;
#pragma unroll
    for (int ks = 0; ks < 2; ++ks) {
      bf16x8 av[4], bv[4];
#pragma unroll
      for (int mi = 0; mi < 4; ++mi) {
        int row = wm * 64 + mi * 16 + lane_lo;
        int usw = (ks * 4 + lane_hi) ^ (row & 7);
        av[mi] = *(const bf16x8*)(AbC + row * 128 + usw * 16);
      }
#pragma unroll
      for (int ni = 0; ni < 4; ++ni) {
        int row = wn * 64 + ni * 16 + lane_lo;
        int usw = (ks * 4 + lane_hi) ^ (row & 7);
        bv[ni] = *(const bf16x8*)(BbC + row * 128 + usw * 16);
      }
#pragma unroll
      for (int mi = 0; mi < 4; ++mi)
#pragma unroll
        for (int ni = 0; ni < 4; ++ni)
          acc[mi][ni] = __builtin_amdgcn_mfma_f32_16x16x32_bf16(av[mi], bv[ni], acc[mi][ni], 0, 0, 0);
    }
  };

  stage(0, 0);
  asm volatile("s_waitcnt vmcnt(0)" ::: "memory");
  __builtin_amdgcn_s_barrier();
  __builtin_amdgcn_sched_barrier(0);
  int cur = 0;
  for (int k0 = 64; k0 < KDIM; k0 += 64) {
    stage(cur ^ 1, k0);
    compute(cur);
    asm volatile("s_waitcnt vmcnt(0)" ::: "memory");
    __builtin_amdgcn_s_barrier();
    __builtin_amdgcn_sched_barrier(0);
    cur ^= 1;
  }
  compute(cur);
}

// FF1: H = gelu(X1 @ W1 + b1), K=512, N=2048 (16 n-blocks); r7 structure.
// H stored with per-128-block column permutation -> 8B packed stores.
__global__ __launch_bounds__(256) void kff1(const u16* __restrict__ X1s,
                                            const u16* __restrict__ W1T,
                                            const float* __restrict__ b1v,
                                            u16* __restrict__ H) {
  __shared__ __align__(16) u16 Ab[8192];
  __shared__ __align__(16) u16 Bb[8192];
  int tid = threadIdx.x, lane = tid & 63, wid = tid >> 6;
  int nwg = gridDim.x, bid = blockIdx.x;
  int m128 = nwg >> 4;
  int xcd = bid & 7, idx = bid >> 3;
  int mb = xcd * (m128 >> 3) + (idx >> 4);
  int nb = idx & 15;
  const u16* Ap = X1s + (size_t)mb * 128 * 512;
  const u16* Bp = W1T + (size_t)nb * 128 * 512;
  f32x4 acc[4][4];
#pragma unroll
  for (int mi = 0; mi < 4; ++mi)
#pragma unroll
    for (int ni = 0; ni < 4; ++ni) acc[mi][ni] = (f32x4){0.f, 0.f, 0.f, 0.f};
  gemm_core_sb<512>(Ap, Bp, Ab, Bb, wid, lane, acc);
  int lane_lo = lane & 15, lane_hi = lane >> 4;
  int wm = wid >> 1, wn = wid & 1;
  float bvals[4];
#pragma unroll
  for (int ni = 0; ni < 4; ++ni) bvals[ni] = b1v[nb * 128 + wn * 64 + ni * 16 + lane_lo];
  int colb = nb * 128 + (wn * 16 + lane_lo) * 4;
#pragma unroll
  for (int mi = 0; mi < 4; ++mi)
#pragma unroll
    for (int j = 0; j < 4; ++j) {
      int rl = wm * 64 + mi * 16 + lane_hi * 4 + j;
      u16x4 pk;
#pragma unroll
      for (int ni = 0; ni < 4; ++ni)
        pk[ni] = f2bf(gelu_f(acc[mi][ni][j] + bvals[ni]));
      *(u16x4*)(H + ((size_t)mb * 128 + rl) * 2048 + colb) = pk;
    }
}

// FF2: P = H @ W2 + b2 + X1 (pre-LN, f32), K=2048, N=512 (4 n-blocks); dbuf core.
__global__ __launch_bounds__(256) void kff2(const u16* __restrict__ H,
                                            const u16* __restrict__ W2T,
                                            const float* __restrict__ b2v,
                                            const u16* __restrict__ X1s,
                                            float* __restrict__ Ps) {
  __shared__ __align__(16) u16 Ab[16384];
  __shared__ __align__(16) u16 Bb[16384];
  int tid = threadIdx.x, lane = tid & 63, wid = tid >> 6;
  int nwg = gridDim.x, bid = blockIdx.x;
  int m128 = nwg >> 2;
  int xcd = bid & 7, idx = bid >> 3;
  int mb = xcd * (m128 >> 3) + (idx >> 2);
  int nb = idx & 3;
  const u16* Ap = H + (size_t)mb * 128 * 2048;
  const u16* Bp = W2T + (size_t)nb * 128 * 2048;
  f32x4 acc[4][4];
#pragma unroll
  for (int mi = 0; mi < 4; ++mi)
#pragma unroll
    for (int ni = 0; ni < 4; ++ni) acc[mi][ni] = (f32x4){0.f, 0.f, 0.f, 0.f};
  gemm_core_db<2048>(Ap, Bp, Ab, Bb, wid, lane, acc);
  int lane_lo = lane & 15, lane_hi = lane >> 4;
  int wm = wid >> 1, wn = wid & 1;
#pragma unroll
  for (int mi = 0; mi < 4; ++mi)
#pragma unroll
    for (int j = 0; j < 4; ++j) {
      int rl = wm * 64 + mi * 16 + lane_hi * 4 + j;
      size_t row = (size_t)mb * 128 + rl;
      const u16* xrow = X1s + row * 512 + nb * 128;
      float* prow = Ps + row * 512 + nb * 128;
#pragma unroll
      for (int ni = 0; ni < 4; ++ni) {
        int col = wn * 64 + ni * 16 + lane_lo;
        prow[col] = acc[mi][ni][j] + b2v[nb * 128 + col] + bf2f(xrow[col]);
      }
    }
}

// LN2 in-place over rows of P (= out): one wave per row
__global__ __launch_bounds__(512) void kln2(float* __restrict__ P,
                                            const float* __restrict__ g2,
                                            const float* __restrict__ bb2) {
  int wid = threadIdx.x >> 6, lane = threadIdx.x & 63;
  size_t row = (size_t)blockIdx.x * 8 + wid;
  float* pr = P + row * 512;
  float4 v0 = *(float4*)(pr + lane * 4);
  float4 v1 = *(float4*)(pr + 256 + lane * 4);
  float s = v0.x + v0.y + v0.z + v0.w + v1.x + v1.y + v1.z + v1.w;
  float q = v0.x * v0.x + v0.y * v0.y + v0.z * v0.z + v0.w * v0.w +
            v1.x * v1.x + v1.y * v1.y + v1.z * v1.z + v1.w * v1.w;
#pragma unroll
  for (int off = 1; off < 64; off <<= 1) { s += __shfl_xor(s, off); q += __shfl_xor(q, off); }
  float mu = s * (1.f / 512.f);
  float rs = rsqrtf(q * (1.f / 512.f) - mu * mu + 512.0f);
  float4 ga = *(const float4*)(g2 + lane * 4);
  float4 gb = *(const float4*)(g2 + 256 + lane * 4);
  float4 ba = *(const float4*)(bb2 + lane * 4);
  float4 bb = *(const float4*)(bb2 + 256 + lane * 4);
  v0.x = (v0.x - mu) * rs * ga.x + ba.x;
  v0.y = (v0.y - mu) * rs * ga.y + ba.y;
  v0.z = (v0.z - mu) * rs * ga.z + ba.z;
  v0.w = (v0.w - mu) * rs * ga.w + ba.w;
  v1.x = (v1.x - mu) * rs * gb.x + bb.x;
  v1.y = (v1.y - mu) * rs * gb.y + bb.y;
  v1.z = (v1.z - mu) * rs * gb.z + bb.z;
  v1.w = (v1.w - mu) * rs * gb.w + bb.w;
  *(float4*)(pr + lane * 4) = v0;
  *(float4*)(pr + 256 + lane * 4) = v1;
}

extern "C" void kernel_launch(void* const* d_in, const int* in_sizes, int n_in,
                              void* d_out, int out_size, void* d_ws, size_t ws_size,
                              hipStream_t stream) {
  const float* x   = (const float*)d_in[0];
  const float* Wq  = (const float*)d_in[1];
  const float* Wk  = (const float*)d_in[2];
  const float* Wv  = (const float*)d_in[3];
  const float* Wp  = (const float*)d_in[4];
  const float* bp  = (const float*)d_in[5];
  const float* W1  = (const float*)d_in[6];
  const float* b1  = (const float*)d_in[7];
  const float* W2  = (const float*)d_in[8];
  const float* b2  = (const float*)d_in[9];
  const float* g1  = (const float*)d_in[10];
  const float* bb1 = (const float*)d_in[11];
  const float* g2  = (const float*)d_in[12];
  const float* bb2 = (const float*)d_in[13];
  float* out = (float*)d_out;

  char* ws = (char*)d_ws;
  float* G  = (float*)ws;                    // 64KB region (256KB reserved)
  u16* WvpT = (u16*)(ws + (256 << 10));      // 128KB
  u16* W1T  = (u16*)(ws + (1 << 20));        // 2MB
  u16* W2T  = (u16*)(ws + (3 << 20));        // 2MB
  u16* Z    = (u16*)(ws + (5 << 20));        // 16MB
  u16* X1   = (u16*)(ws + (21 << 20));       // 64MB
  u16* H    = (u16*)(ws + (85ull << 20));    // H slice region

  hipLaunchKernelGGL(kprep_G,   dim3(64),   dim3(256), 0, stream, Wq, Wk, G);
  hipLaunchKernelGGL(kprep_Wvp, dim3(256),  dim3(256), 0, stream, Wv, Wp, WvpT);
  hipLaunchKernelGGL(kprep_W1T, dim3(4096), dim3(256), 0, stream, W1, W1T);
  hipLaunchKernelGGL(kprep_W2T, dim3(4096), dim3(256), 0, stream, W2, W2T);
  hipLaunchKernelGGL(ktoken,    dim3(4096), dim3(256), 0, stream, x, G, Z);
  hipLaunchKernelGGL(kattn,     dim3(1024), dim3(512), 0, stream, Z, WvpT, bp, x, g1, bb1, X1);

  // S>=4 so each H slice (<=64MB) is L3-resident between kff1 and kff2
  const size_t hbase = 85ull << 20;
  int S = 64;
  for (int c = 4; c <= 64; c <<= 1) {
    if (hbase + (268435456ull / (size_t)c) <= ws_size) { S = c; break; }
  }
  int Ms = MROWS / S;   // 16384 rows at S=4
  for (int s = 0; s < S; ++s) {
    const u16* x1s = X1 + (size_t)s * Ms * 512;
    float* outs = out + (size_t)s * Ms * 512;
    hipLaunchKernelGGL(kff1, dim3((Ms / 128) * 16), dim3(256), 0, stream, x1s, W1T, b1, H);
    hipLaunchKernelGGL(kff2, dim3((Ms / 128) * 4),  dim3(256), 0, stream, H, W2T, b2, x1s, outs);
  }
  hipLaunchKernelGGL(kln2, dim3(8192), dim3(512), 0, stream, out, g2, bb2);
}

// Round 12
// 631.847 us; speedup vs baseline: 1.2329x; 1.0706x over previous
//
#include <hip/hip_runtime.h>
#include <hip/hip_bf16.h>
#include <math.h>

typedef __bf16 bf16x8 __attribute__((ext_vector_type(8)));
typedef float f32x4 __attribute__((ext_vector_type(4)));
typedef unsigned short u16;
typedef unsigned int u32;
typedef u16 u16x4 __attribute__((ext_vector_type(4)));
typedef u16 u16x8 __attribute__((ext_vector_type(8)));

#define TOKENS 16384
#define MROWS  65536

__device__ __forceinline__ u16 f2bf(float f) {
  union { __hip_bfloat16 h; u16 u; } c;
  c.h = __float2bfloat16(f);
  return c.u;
}
__device__ __forceinline__ float bf2f(u16 u) {
  union { u16 u; __hip_bfloat16 h; } c;
  c.u = u;
  return __bfloat162float(c.h);
}
// sigmoid-form gelu (validated r6-r11, absmax 6.1e-5)
__device__ __forceinline__ float gelu_f(float u) {
  float y2 = u * fmaf(0.07135481283f, u * u, 1.595769122f);
  float e = __expf(-y2);
  return u / (1.f + e);
}
// async global->LDS, 16B per lane; LDS dest is wave-uniform base + lane*16
__device__ __forceinline__ void gload16(const void* g, void* l) {
  __builtin_amdgcn_global_load_lds(
      (const __attribute__((address_space(1))) void*)g,
      (__attribute__((address_space(3))) void*)l, 16, 0, 0);
}

// ---------------- prep kernels ----------------
// Gbf[c][c2] = bf16( (1/sqrt(512)) * sum_d Wq[c][d]*Wk[c2][d] )   (128x128)
__global__ void kprep_G(const float* __restrict__ Wq, const float* __restrict__ Wk,
                        u16* __restrict__ Gbf) {
  int id = blockIdx.x * 256 + threadIdx.x;  // 16384
  int c = id >> 7, c2 = id & 127;
  const float4* a = (const float4*)(Wq + (size_t)c * 512);
  const float4* b = (const float4*)(Wk + (size_t)c2 * 512);
  float s = 0.f;
#pragma unroll 8
  for (int i = 0; i < 128; ++i) {
    float4 xa = a[i], yb = b[i];
    s += xa.x * yb.x + xa.y * yb.y + xa.z * yb.z + xa.w * yb.w;
  }
  Gbf[id] = f2bf(s * 0.044194173824159216f);
}

__global__ void kprep_Wvp(const float* __restrict__ Wv, const float* __restrict__ Wp,
                          u16* __restrict__ WvpT) {
  int id = blockIdx.x * 256 + threadIdx.x;  // 65536 : e*128+c
  int e = id >> 7, c = id & 127;
  float s = 0.f;
#pragma unroll 4
  for (int d = 0; d < 512; ++d) s += Wv[(size_t)c * 512 + d] * Wp[(size_t)d * 512 + e];
  WvpT[id] = f2bf(s);
}

// W1T[f][e] = bf16(W1[e][f]) via 64x64 LDS tile: coalesced reads AND writes.
// grid (32, 8): blockIdx.x = f-tile, blockIdx.y = e-tile; 256 threads.
__global__ __launch_bounds__(256) void kprep_W1T(const float* __restrict__ W1,
                                                 u16* __restrict__ W1T) {
  __shared__ u16 Lt[64][72];  // [e_local][f_local]
  int tid = threadIdx.x;
  int bf = blockIdx.x, be = blockIdx.y;
#pragma unroll
  for (int rnd = 0; rnd < 4; ++rnd) {
    int r = rnd * 16 + (tid >> 4);          // e_local
    int f4 = (tid & 15) * 4;                // f_local
    float4 v = *(const float4*)(W1 + (size_t)(be * 64 + r) * 2048 + bf * 64 + f4);
    Lt[r][f4] = f2bf(v.x); Lt[r][f4 + 1] = f2bf(v.y);
    Lt[r][f4 + 2] = f2bf(v.z); Lt[r][f4 + 3] = f2bf(v.w);
  }
  __syncthreads();
  int fl = tid >> 2, eg = (tid & 3) * 16;
  u16x8 o0, o1;
#pragma unroll
  for (int q = 0; q < 8; ++q) { o0[q] = Lt[eg + q][fl]; o1[q] = Lt[eg + 8 + q][fl]; }
  u16* dst = W1T + (size_t)(bf * 64 + fl) * 512 + be * 64 + eg;
  *(u16x8*)dst = o0;
  *(u16x8*)(dst + 8) = o1;
}

// W2T[e][fst] = bf16(W2[f_true][e]), H-column permutation per 128-block:
// fst = fb*128 + a*64 + fs', f_true = fb*128 + a*64 + (fs'&3)*16 + ((fs'>>2)&15)
// (identical mapping to r7-r11's formula; validated). Tiled for coalescing.
// grid (32, 8): blockIdx.x = f-tile (64 rows of W2), blockIdx.y = e-tile.
__global__ __launch_bounds__(256) void kprep_W2T(const float* __restrict__ W2,
                                                 u16* __restrict__ W2T) {
  __shared__ u16 Lt[64][72];  // [f_local][e_local]
  int tid = threadIdx.x;
  int bf = blockIdx.x, be = blockIdx.y;
#pragma unroll
  for (int rnd = 0; rnd < 4; ++rnd) {
    int r = rnd * 16 + (tid >> 4);          // f_local
    int e4 = (tid & 15) * 4;                // e_local
    float4 v = *(const float4*)(W2 + (size_t)(bf * 64 + r) * 512 + be * 64 + e4);
    Lt[r][e4] = f2bf(v.x); Lt[r][e4 + 1] = f2bf(v.y);
    Lt[r][e4 + 2] = f2bf(v.z); Lt[r][e4 + 3] = f2bf(v.w);
  }
  __syncthreads();
  int aa = bf & 1, fb = bf >> 1;
  int el = tid >> 2, g = tid & 3;
  u16x8 o0, o1;
#pragma unroll
  for (int q = 0; q < 8; ++q) {
    int fs0 = g * 16 + q, fs1 = g * 16 + 8 + q;
    o0[q] = Lt[(fs0 & 3) * 16 + ((fs0 >> 2) & 15)][el];
    o1[q] = Lt[(fs1 & 3) * 16 + ((fs1 >> 2) & 15)][el];
  }
  u16* dst = W2T + (size_t)(be * 64 + el) * 2048 + fb * 128 + aa * 64 + g * 16;
  *(u16x8*)dst = o0;
  *(u16x8*)(dst + 8) = o1;
}

// ---------------- token attention: Z = softmax(mask(S G S^T)) S ----------------
// One wave per token, 4/block. G staged once per block as bf16 (32KB LDS);
// T1 in registers; wei via all-lane partials + 16x6 shfl_xor butterfly.
// One barrier total; no MFMA; Z layout unchanged.
__global__ __launch_bounds__(256) void ktoken(const float* __restrict__ x,
                                              const u16* __restrict__ Gbf,
                                              u16* __restrict__ Z) {
  __shared__ float Ss[4 * 512];            // 8 KB
  __shared__ __align__(16) u16 Gs[16384];  // 32 KB [c][c2]
  int tid = threadIdx.x;
  int wave = tid >> 6, lane = tid & 63;
  int tok = blockIdx.x * 4 + wave;
  char* GsC = (char*)Gs;
#pragma unroll
  for (int it = 0; it < 8; ++it)
    gload16(Gbf + (size_t)(it * 256 + tid) * 8, GsC + it * 4096 + wave * 1024);
  {
    const float4* xs = (const float4*)(x + (size_t)tok * 512);
    float4* sw = (float4*)(Ss + wave * 512);
    sw[lane] = xs[lane];
    sw[64 + lane] = xs[64 + lane];
  }
  __syncthreads();  // G staged (vmcnt drained) + S visible

  const float* Sw = Ss + wave * 512;
  const u32* Grow = (const u32*)Gs;  // row c at u32 index c*64 + lane (cols 2lane,2lane+1)
  float a[4][2] = {{0.f, 0.f}, {0.f, 0.f}, {0.f, 0.f}, {0.f, 0.f}};
#pragma unroll 4
  for (int c = 0; c < 128; ++c) {
    u32 g2 = Grow[c * 64 + lane];
    float glo = __uint_as_float(g2 << 16);
    float ghi = __uint_as_float(g2 & 0xFFFF0000u);
    float s0 = Sw[c], s1 = Sw[128 + c], s2 = Sw[256 + c], s3 = Sw[384 + c];
    a[0][0] += s0 * glo; a[0][1] += s0 * ghi;
    a[1][0] += s1 * glo; a[1][1] += s1 * ghi;
    a[2][0] += s2 * glo; a[2][1] += s2 * ghi;
    a[3][0] += s3 * glo; a[3][1] += s3 * ghi;
  }
  // wei[i][j] = sum_lanes (a[i][0]*S[j][2lane] + a[i][1]*S[j][2lane+1])
  float w[16];
#pragma unroll
  for (int j = 0; j < 4; ++j) {
    float sj0 = Sw[j * 128 + 2 * lane];
    float sj1 = Sw[j * 128 + 2 * lane + 1];
#pragma unroll
    for (int i = 0; i < 4; ++i)
      w[i * 4 + j] = a[i][0] * sj0 + a[i][1] * sj1;
  }
#pragma unroll
  for (int off = 1; off < 64; off <<= 1)
#pragma unroll
    for (int k = 0; k < 16; ++k) w[k] += __shfl_xor(w[k], off);
  // causal softmax (all lanes redundant, registers only)
  float p[4][4];
#pragma unroll
  for (int i = 0; i < 4; ++i) {
    float m = w[i * 4];
    for (int j = 1; j <= i; ++j) m = fmaxf(m, w[i * 4 + j]);
    float s = 0.f;
    for (int j = 0; j <= i; ++j) { p[i][j] = __expf(w[i * 4 + j] - m); s += p[i][j]; }
    float inv = 1.f / s;
    for (int j = 0; j <= i; ++j) p[i][j] *= inv;
    for (int j = i + 1; j < 4; ++j) p[i][j] = 0.f;
  }
  // Z = P @ S  (cols 2lane, 2lane+1)
  int c = lane * 2;
  u32* zout = (u32*)(Z + (size_t)tok * 512);
#pragma unroll
  for (int i = 0; i < 4; ++i) {
    float z0 = 0.f, z1 = 0.f;
#pragma unroll
    for (int j = 0; j < 4; ++j) {
      z0 += p[i][j] * Sw[j * 128 + c];
      z1 += p[i][j] * Sw[j * 128 + c + 1];
    }
    zout[i * 64 + lane] = (u32)f2bf(z0) | ((u32)f2bf(z1) << 16);
  }
}

// ---------------- attn-out projection + bias + residual + LN1 -> X1 (bf16) ----------------
__global__ __launch_bounds__(512) void kattn(const u16* __restrict__ Z,
                                             const u16* __restrict__ WvpT,
                                             const float* __restrict__ bp,
                                             const float* __restrict__ x,
                                             const float* __restrict__ g1,
                                             const float* __restrict__ bln1,
                                             u16* __restrict__ X1) {
  __shared__ u16 AO[32768];
  __shared__ float rsum[64 * 4];
  __shared__ float rsq[64 * 4];
  __shared__ float mus[64];
  __shared__ float rss[64];
  char* smem = (char*)AO;
  int tid = threadIdx.x;
  int lane = tid & 63, wid = tid >> 6;
  int wm = wid >> 2, wnq = wid & 3;
  int lane_lo = lane & 15, lane_hi = lane >> 4;
  int m0 = blockIdx.x * 64;
  {
    const bf16x8* src = (const bf16x8*)(Z + (size_t)m0 * 128);
#pragma unroll
    for (int it = 0; it < 2; ++it) {
      int idx8 = it * 512 + tid;
      int row = idx8 >> 4;
      int byte = (idx8 * 16) ^ ((row & 7) << 4);
      *(bf16x8*)(smem + byte) = src[idx8];
    }
  }
  __syncthreads();
  f32x4 acc[2][8];
#pragma unroll
  for (int mi = 0; mi < 2; ++mi)
#pragma unroll
    for (int ni = 0; ni < 8; ++ni) acc[mi][ni] = (f32x4){0.f, 0.f, 0.f, 0.f};
#pragma unroll
  for (int ks = 0; ks < 4; ++ks) {
    bf16x8 af[2];
#pragma unroll
    for (int mi = 0; mi < 2; ++mi) {
      int row = wm * 32 + mi * 16 + lane_lo;
      int byte = (row * 256 + (ks * 32 + lane_hi * 8) * 2) ^ ((row & 7) << 4);
      af[mi] = *(const bf16x8*)(smem + byte);
    }
#pragma unroll
    for (int ni = 0; ni < 8; ++ni) {
      int n = wnq * 128 + ni * 16 + lane_lo;
      bf16x8 bfr = *(const bf16x8*)(WvpT + (size_t)n * 128 + ks * 32 + lane_hi * 8);
#pragma unroll
      for (int mi = 0; mi < 2; ++mi)
        acc[mi][ni] = __builtin_amdgcn_mfma_f32_16x16x32_bf16(af[mi], bfr, acc[mi][ni], 0, 0, 0);
    }
  }
#pragma unroll
  for (int mi = 0; mi < 2; ++mi) {
#pragma unroll
    for (int j = 0; j < 4; ++j) {
      int rl = wm * 32 + mi * 16 + lane_hi * 4 + j;
      int R = m0 + rl;
      const float* xrow = x + (size_t)(R >> 2) * 512;
      float s = 0.f, q = 0.f;
#pragma unroll
      for (int ni = 0; ni < 8; ++ni) {
        int col = wnq * 128 + ni * 16 + lane_lo;
        float val = acc[mi][ni][j] + bp[col] + xrow[col];
        acc[mi][ni][j] = val;
        s += val; q += val * val;
      }
#pragma unroll
      for (int off = 1; off < 16; off <<= 1) { s += __shfl_xor(s, off); q += __shfl_xor(q, off); }
      if (lane_lo == 0) { rsum[rl * 4 + wnq] = s; rsq[rl * 4 + wnq] = q; }
    }
  }
  __syncthreads();
  if (tid < 64) {
    float s = rsum[tid * 4] + rsum[tid * 4 + 1] + rsum[tid * 4 + 2] + rsum[tid * 4 + 3];
    float q = rsq[tid * 4] + rsq[tid * 4 + 1] + rsq[tid * 4 + 2] + rsq[tid * 4 + 3];
    float mu = s * (1.f / 512.f);
    float var = q * (1.f / 512.f) - mu * mu;
    mus[tid] = mu;
    rss[tid] = rsqrtf(var + 512.0f);
  }
  __syncthreads();
#pragma unroll
  for (int mi = 0; mi < 2; ++mi) {
#pragma unroll
    for (int j = 0; j < 4; ++j) {
      int rl = wm * 32 + mi * 16 + lane_hi * 4 + j;
      float mu = mus[rl], rs = rss[rl];
#pragma unroll
      for (int ni = 0; ni < 8; ++ni) {
        int col = wnq * 128 + ni * 16 + lane_lo;
        AO[rl * 512 + col] = f2bf((acc[mi][ni][j] - mu) * rs * g1[col] + bln1[col]);
      }
    }
  }
  __syncthreads();
  {
    bf16x8* dst = (bf16x8*)(X1 + (size_t)m0 * 512);
    const bf16x8* s8 = (const bf16x8*)AO;
#pragma unroll
    for (int it = 0; it < 8; ++it) dst[it * 512 + tid] = s8[it * 512 + tid];
  }
}

// ======== single-buffered m97-style GEMM core (r7: best for short-K kff1) ========
template<int KDIM>
__device__ __forceinline__ void gemm_core_sb(const u16* __restrict__ Ap,
                                             const u16* __restrict__ Bp,
                                             u16* Ab, u16* Bb,
                                             int wid, int lane, f32x4 acc[4][4]) {
  const int lane_lo = lane & 15, lane_hi = lane >> 4;
  const int wm = wid >> 1, wn = wid & 1;
  const int rl8 = lane >> 3, u8 = lane & 7;
  char* AbC = (char*)Ab;
  char* BbC = (char*)Bb;
  for (int k0 = 0; k0 < KDIM; k0 += 64) {
#pragma unroll
    for (int i = 0; i < 4; ++i) {
      int row = wid * 32 + i * 8 + rl8;
      int usw = u8 ^ (row & 7);
      size_t goff = (size_t)row * KDIM + k0 + usw * 8;
      gload16(Ap + goff, AbC + wid * 4096 + i * 1024);
      gload16(Bp + goff, BbC + wid * 4096 + i * 1024);
    }
    __syncthreads();
#pragma unroll
    for (int ks = 0; ks < 2; ++ks) {
      bf16x8 av[4], bv[4];
#pragma unroll
      for (int mi = 0; mi < 4; ++mi) {
        int row = wm * 64 + mi * 16 + lane_lo;
        int usw = (ks * 4 + lane_hi) ^ (row & 7);
        av[mi] = *(const bf16x8*)(AbC + row * 128 + usw * 16);
      }
#pragma unroll
      for (int ni = 0; ni < 4; ++ni) {
        int row = wn * 64 + ni * 16 + lane_lo;
        int usw = (ks * 4 + lane_hi) ^ (row & 7);
        bv[ni] = *(const bf16x8*)(BbC + row * 128 + usw * 16);
      }
#pragma unroll
      for (int mi = 0; mi < 4; ++mi)
#pragma unroll
        for (int ni = 0; ni < 4; ++ni)
          acc[mi][ni] = __builtin_amdgcn_mfma_f32_16x16x32_bf16(av[mi], bv[ni], acc[mi][ni], 0, 0, 0);
    }
    __syncthreads();
  }
}

// ======== 2-phase double-buffered core (r8: best for long-K, H-streaming kff2) ========
template<int KDIM>
__device__ __forceinline__ void gemm_core_db(const u16* __restrict__ Ap,
                                             const u16* __restrict__ Bp,
                                             u16* AbBase, u16* BbBase,
                                             int wid, int lane, f32x4 acc[4][4]) {
  const int lane_lo = lane & 15, lane_hi = lane >> 4;
  const int wm = wid >> 1, wn = wid & 1;
  const int rl8 = lane >> 3, u8 = lane & 7;

  auto stage = [&](int buf, int k0) {
    char* AbC = (char*)AbBase + buf * 16384;
    char* BbC = (char*)BbBase + buf * 16384;
#pragma unroll
    for (int i = 0; i < 4; ++i) {
      int row = wid * 32 + i * 8 + rl8;
      int usw = u8 ^ (row & 7);
      size_t goff = (size_t)row * KDIM + k0 + usw * 8;
      gload16(Ap + goff, AbC + wid * 4096 + i * 1024);
      gload16(Bp + goff, BbC + wid * 4096 + i * 1024);
    }
  };
  auto compute = [&](int buf) {
    char* AbC = (char*)AbBase + buf * 16384;
    char* BbC = (char*)BbBase + buf * 16384;
#pragma unroll
    for (int ks = 0; ks < 2; ++ks) {
      bf16x8 av[4], bv[4];
#pragma unroll
      for (int mi = 0; mi < 4; ++mi) {
        int row = wm * 64 + mi * 16 + lane_lo;
        int usw = (ks * 4 + lane_hi) ^ (row & 7);
        av[mi] = *(const bf16x8*)(AbC + row * 128 + usw * 16);
      }
#pragma unroll
      for (int ni = 0; ni < 4; ++ni) {
        int row = wn * 64 + ni * 16 + lane_lo;
        int usw = (ks * 4 + lane_hi) ^ (row & 7);
        bv[ni] = *(const bf16x8*)(BbC + row * 128 + usw * 16);
      }
#pragma unroll
      for (int mi = 0; mi < 4; ++mi)
#pragma unroll
        for (int ni = 0; ni < 4; ++ni)
          acc[mi][ni] = __builtin_amdgcn_mfma_f32_16x16x32_bf16(av[mi], bv[ni], acc[mi][ni], 0, 0, 0);
    }
  };

  stage(0, 0);
  asm volatile("s_waitcnt vmcnt(0)" ::: "memory");
  __builtin_amdgcn_s_barrier();
  __builtin_amdgcn_sched_barrier(0);
  int cur = 0;
  for (int k0 = 64; k0 < KDIM; k0 += 64) {
    stage(cur ^ 1, k0);
    compute(cur);
    asm volatile("s_waitcnt vmcnt(0)" ::: "memory");
    __builtin_amdgcn_s_barrier();
    __builtin_amdgcn_sched_barrier(0);
    cur ^= 1;
  }
  compute(cur);
}

// FF1: H = gelu(X1 @ W1 + b1), K=512, N=2048 (16 n-blocks); r7 structure.
__global__ __launch_bounds__(256) void kff1(const u16* __restrict__ X1s,
                                            const u16* __restrict__ W1T,
                                            const float* __restrict__ b1v,
                                            u16* __restrict__ H) {
  __shared__ __align__(16) u16 Ab[8192];
  __shared__ __align__(16) u16 Bb[8192];
  int tid = threadIdx.x, lane = tid & 63, wid = tid >> 6;
  int nwg = gridDim.x, bid = blockIdx.x;
  int m128 = nwg >> 4;
  int xcd = bid & 7, idx = bid >> 3;
  int mb = xcd * (m128 >> 3) + (idx >> 4);
  int nb = idx & 15;
  const u16* Ap = X1s + (size_t)mb * 128 * 512;
  const u16* Bp = W1T + (size_t)nb * 128 * 512;
  f32x4 acc[4][4];
#pragma unroll
  for (int mi = 0; mi < 4; ++mi)
#pragma unroll
    for (int ni = 0; ni < 4; ++ni) acc[mi][ni] = (f32x4){0.f, 0.f, 0.f, 0.f};
  gemm_core_sb<512>(Ap, Bp, Ab, Bb, wid, lane, acc);
  int lane_lo = lane & 15, lane_hi = lane >> 4;
  int wm = wid >> 1, wn = wid & 1;
  float bvals[4];
#pragma unroll
  for (int ni = 0; ni < 4; ++ni) bvals[ni] = b1v[nb * 128 + wn * 64 + ni * 16 + lane_lo];
  int colb = nb * 128 + (wn * 16 + lane_lo) * 4;
#pragma unroll
  for (int mi = 0; mi < 4; ++mi)
#pragma unroll
    for (int j = 0; j < 4; ++j) {
      int rl = wm * 64 + mi * 16 + lane_hi * 4 + j;
      u16x4 pk;
#pragma unroll
      for (int ni = 0; ni < 4; ++ni)
        pk[ni] = f2bf(gelu_f(acc[mi][ni][j] + bvals[ni]));
      *(u16x4*)(H + ((size_t)mb * 128 + rl) * 2048 + colb) = pk;
    }
}

// FF2: P = H @ W2 + b2 + X1 (pre-LN, f32), K=2048, N=512 (4 n-blocks); dbuf core.
__global__ __launch_bounds__(256) void kff2(const u16* __restrict__ H,
                                            const u16* __restrict__ W2T,
                                            const float* __restrict__ b2v,
                                            const u16* __restrict__ X1s,
                                            float* __restrict__ Ps) {
  __shared__ __align__(16) u16 Ab[16384];
  __shared__ __align__(16) u16 Bb[16384];
  int tid = threadIdx.x, lane = tid & 63, wid = tid >> 6;
  int nwg = gridDim.x, bid = blockIdx.x;
  int m128 = nwg >> 2;
  int xcd = bid & 7, idx = bid >> 3;
  int mb = xcd * (m128 >> 3) + (idx >> 2);
  int nb = idx & 3;
  const u16* Ap = H + (size_t)mb * 128 * 2048;
  const u16* Bp = W2T + (size_t)nb * 128 * 2048;
  f32x4 acc[4][4];
#pragma unroll
  for (int mi = 0; mi < 4; ++mi)
#pragma unroll
    for (int ni = 0; ni < 4; ++ni) acc[mi][ni] = (f32x4){0.f, 0.f, 0.f, 0.f};
  gemm_core_db<2048>(Ap, Bp, Ab, Bb, wid, lane, acc);
  int lane_lo = lane & 15, lane_hi = lane >> 4;
  int wm = wid >> 1, wn = wid & 1;
#pragma unroll
  for (int mi = 0; mi < 4; ++mi)
#pragma unroll
    for (int j = 0; j < 4; ++j) {
      int rl = wm * 64 + mi * 16 + lane_hi * 4 + j;
      size_t row = (size_t)mb * 128 + rl;
      const u16* xrow = X1s + row * 512 + nb * 128;
      float* prow = Ps + row * 512 + nb * 128;
#pragma unroll
      for (int ni = 0; ni < 4; ++ni) {
        int col = wn * 64 + ni * 16 + lane_lo;
        prow[col] = acc[mi][ni][j] + b2v[nb * 128 + col] + bf2f(xrow[col]);
      }
    }
}

// LN2 in-place over rows of P (= out): one wave per row
__global__ __launch_bounds__(512) void kln2(float* __restrict__ P,
                                            const float* __restrict__ g2,
                                            const float* __restrict__ bb2) {
  int wid = threadIdx.x >> 6, lane = threadIdx.x & 63;
  size_t row = (size_t)blockIdx.x * 8 + wid;
  float* pr = P + row * 512;
  float4 v0 = *(float4*)(pr + lane * 4);
  float4 v1 = *(float4*)(pr + 256 + lane * 4);
  float s = v0.x + v0.y + v0.z + v0.w + v1.x + v1.y + v1.z + v1.w;
  float q = v0.x * v0.x + v0.y * v0.y + v0.z * v0.z + v0.w * v0.w +
            v1.x * v1.x + v1.y * v1.y + v1.z * v1.z + v1.w * v1.w;
#pragma unroll
  for (int off = 1; off < 64; off <<= 1) { s += __shfl_xor(s, off); q += __shfl_xor(q, off); }
  float mu = s * (1.f / 512.f);
  float rs = rsqrtf(q * (1.f / 512.f) - mu * mu + 512.0f);
  float4 ga = *(const float4*)(g2 + lane * 4);
  float4 gb = *(const float4*)(g2 + 256 + lane * 4);
  float4 ba = *(const float4*)(bb2 + lane * 4);
  float4 bb = *(const float4*)(bb2 + 256 + lane * 4);
  v0.x = (v0.x - mu) * rs * ga.x + ba.x;
  v0.y = (v0.y - mu) * rs * ga.y + ba.y;
  v0.z = (v0.z - mu) * rs * ga.z + ba.z;
  v0.w = (v0.w - mu) * rs * ga.w + ba.w;
  v1.x = (v1.x - mu) * rs * gb.x + bb.x;
  v1.y = (v1.y - mu) * rs * gb.y + bb.y;
  v1.z = (v1.z - mu) * rs * gb.z + bb.z;
  v1.w = (v1.w - mu) * rs * gb.w + bb.w;
  *(float4*)(pr + lane * 4) = v0;
  *(float4*)(pr + 256 + lane * 4) = v1;
}

extern "C" void kernel_launch(void* const* d_in, const int* in_sizes, int n_in,
                              void* d_out, int out_size, void* d_ws, size_t ws_size,
                              hipStream_t stream) {
  const float* x   = (const float*)d_in[0];
  const float* Wq  = (const float*)d_in[1];
  const float* Wk  = (const float*)d_in[2];
  const float* Wv  = (const float*)d_in[3];
  const float* Wp  = (const float*)d_in[4];
  const float* bp  = (const float*)d_in[5];
  const float* W1  = (const float*)d_in[6];
  const float* b1  = (const float*)d_in[7];
  const float* W2  = (const float*)d_in[8];
  const float* b2  = (const float*)d_in[9];
  const float* g1  = (const float*)d_in[10];
  const float* bb1 = (const float*)d_in[11];
  const float* g2  = (const float*)d_in[12];
  const float* bb2 = (const float*)d_in[13];
  float* out = (float*)d_out;

  char* ws = (char*)d_ws;
  u16* Gbf  = (u16*)ws;                      // 32KB (region reserved 256KB)
  u16* WvpT = (u16*)(ws + (256 << 10));      // 128KB
  u16* W1T  = (u16*)(ws + (1 << 20));        // 2MB
  u16* W2T  = (u16*)(ws + (3 << 20));        // 2MB
  u16* Z    = (u16*)(ws + (5 << 20));        // 16MB
  u16* X1   = (u16*)(ws + (21 << 20));       // 64MB
  u16* H    = (u16*)(ws + (85ull << 20));    // H slice region

  hipLaunchKernelGGL(kprep_G,   dim3(64),        dim3(256), 0, stream, Wq, Wk, Gbf);
  hipLaunchKernelGGL(kprep_Wvp, dim3(256),       dim3(256), 0, stream, Wv, Wp, WvpT);
  hipLaunchKernelGGL(kprep_W1T, dim3(32, 8),     dim3(256), 0, stream, W1, W1T);
  hipLaunchKernelGGL(kprep_W2T, dim3(32, 8),     dim3(256), 0, stream, W2, W2T);
  hipLaunchKernelGGL(ktoken,    dim3(4096),      dim3(256), 0, stream, x, Gbf, Z);
  hipLaunchKernelGGL(kattn,     dim3(1024),      dim3(512), 0, stream, Z, WvpT, bp, x, g1, bb1, X1);

  // S>=4 so each H slice (<=64MB) is L3-resident between kff1 and kff2
  const size_t hbase = 85ull << 20;
  int S = 64;
  for (int c = 4; c <= 64; c <<= 1) {
    if (hbase + (268435456ull / (size_t)c) <= ws_size) { S = c; break; }
  }
  int Ms = MROWS / S;   // 16384 rows at S=4
  for (int s = 0; s < S; ++s) {
    const u16* x1s = X1 + (size_t)s * Ms * 512;
    float* outs = out + (size_t)s * Ms * 512;
    hipLaunchKernelGGL(kff1, dim3((Ms / 128) * 16), dim3(256), 0, stream, x1s, W1T, b1, H);
    hipLaunchKernelGGL(kff2, dim3((Ms / 128) * 4),  dim3(256), 0, stream, H, W2T, b2, x1s, outs);
  }
  hipLaunchKernelGGL(kln2, dim3(8192), dim3(512), 0, stream, out, g2, bb2);
}

// Round 13
// 596.601 us; speedup vs baseline: 1.3057x; 1.0591x over previous
//
#include <hip/hip_runtime.h>
#include <hip/hip_bf16.h>
#include <math.h>

typedef __bf16 bf16x8 __attribute__((ext_vector_type(8)));
typedef float f32x4 __attribute__((ext_vector_type(4)));
typedef unsigned short u16;
typedef unsigned int u32;
typedef u16 u16x4 __attribute__((ext_vector_type(4)));
typedef u16 u16x8 __attribute__((ext_vector_type(8)));

#define TOKENS 16384
#define MROWS  65536

__device__ __forceinline__ u16 f2bf(float f) {
  union { __hip_bfloat16 h; u16 u; } c;
  c.h = __float2bfloat16(f);
  return c.u;
}
__device__ __forceinline__ float bf2f(u16 u) {
  union { u16 u; __hip_bfloat16 h; } c;
  c.u = u;
  return __bfloat162float(c.h);
}
// sigmoid-form gelu (validated r6-r12, absmax 6.1e-5)
__device__ __forceinline__ float gelu_f(float u) {
  float y2 = u * fmaf(0.07135481283f, u * u, 1.595769122f);
  float e = __expf(-y2);
  return u / (1.f + e);
}
// async global->LDS, 16B per lane; LDS dest is wave-uniform base + lane*16
__device__ __forceinline__ void gload16(const void* g, void* l) {
  __builtin_amdgcn_global_load_lds(
      (const __attribute__((address_space(1))) void*)g,
      (__attribute__((address_space(3))) void*)l, 16, 0, 0);
}

// ---------------- prep kernels ----------------
// Gbf[c][c2] = bf16( (1/sqrt(512)) * sum_d Wq[c][d]*Wk[c2][d] )   (128x128)
__global__ void kprep_G(const float* __restrict__ Wq, const float* __restrict__ Wk,
                        u16* __restrict__ Gbf) {
  int id = blockIdx.x * 256 + threadIdx.x;  // 16384
  int c = id >> 7, c2 = id & 127;
  const float4* a = (const float4*)(Wq + (size_t)c * 512);
  const float4* b = (const float4*)(Wk + (size_t)c2 * 512);
  float s = 0.f;
#pragma unroll 8
  for (int i = 0; i < 128; ++i) {
    float4 xa = a[i], yb = b[i];
    s += xa.x * yb.x + xa.y * yb.y + xa.z * yb.z + xa.w * yb.w;
  }
  Gbf[id] = f2bf(s * 0.044194173824159216f);
}

__global__ void kprep_Wvp(const float* __restrict__ Wv, const float* __restrict__ Wp,
                          u16* __restrict__ WvpT) {
  int id = blockIdx.x * 256 + threadIdx.x;  // 65536 : e*128+c
  int e = id >> 7, c = id & 127;
  float s = 0.f;
#pragma unroll 4
  for (int d = 0; d < 512; ++d) s += Wv[(size_t)c * 512 + d] * Wp[(size_t)d * 512 + e];
  WvpT[id] = f2bf(s);
}

// W1T[f][e] = bf16(W1[e][f]) via 64x64 LDS tile: coalesced reads AND writes.
__global__ __launch_bounds__(256) void kprep_W1T(const float* __restrict__ W1,
                                                 u16* __restrict__ W1T) {
  __shared__ u16 Lt[64][72];  // [e_local][f_local]
  int tid = threadIdx.x;
  int bf = blockIdx.x, be = blockIdx.y;
#pragma unroll
  for (int rnd = 0; rnd < 4; ++rnd) {
    int r = rnd * 16 + (tid >> 4);          // e_local
    int f4 = (tid & 15) * 4;                // f_local
    float4 v = *(const float4*)(W1 + (size_t)(be * 64 + r) * 2048 + bf * 64 + f4);
    Lt[r][f4] = f2bf(v.x); Lt[r][f4 + 1] = f2bf(v.y);
    Lt[r][f4 + 2] = f2bf(v.z); Lt[r][f4 + 3] = f2bf(v.w);
  }
  __syncthreads();
  int fl = tid >> 2, eg = (tid & 3) * 16;
  u16x8 o0, o1;
#pragma unroll
  for (int q = 0; q < 8; ++q) { o0[q] = Lt[eg + q][fl]; o1[q] = Lt[eg + 8 + q][fl]; }
  u16* dst = W1T + (size_t)(bf * 64 + fl) * 512 + be * 64 + eg;
  *(u16x8*)dst = o0;
  *(u16x8*)(dst + 8) = o1;
}

// W2T[e][fst] = bf16(W2[f_true][e]), H-column permutation per 128-block (validated).
__global__ __launch_bounds__(256) void kprep_W2T(const float* __restrict__ W2,
                                                 u16* __restrict__ W2T) {
  __shared__ u16 Lt[64][72];  // [f_local][e_local]
  int tid = threadIdx.x;
  int bf = blockIdx.x, be = blockIdx.y;
#pragma unroll
  for (int rnd = 0; rnd < 4; ++rnd) {
    int r = rnd * 16 + (tid >> 4);          // f_local
    int e4 = (tid & 15) * 4;                // e_local
    float4 v = *(const float4*)(W2 + (size_t)(bf * 64 + r) * 512 + be * 64 + e4);
    Lt[r][e4] = f2bf(v.x); Lt[r][e4 + 1] = f2bf(v.y);
    Lt[r][e4 + 2] = f2bf(v.z); Lt[r][e4 + 3] = f2bf(v.w);
  }
  __syncthreads();
  int aa = bf & 1, fb = bf >> 1;
  int el = tid >> 2, g = tid & 3;
  u16x8 o0, o1;
#pragma unroll
  for (int q = 0; q < 8; ++q) {
    int fs0 = g * 16 + q, fs1 = g * 16 + 8 + q;
    o0[q] = Lt[(fs0 & 3) * 16 + ((fs0 >> 2) & 15)][el];
    o1[q] = Lt[(fs1 & 3) * 16 + ((fs1 >> 2) & 15)][el];
  }
  u16* dst = W2T + (size_t)(be * 64 + el) * 2048 + fb * 128 + aa * 64 + g * 16;
  *(u16x8*)dst = o0;
  *(u16x8*)(dst + 8) = o1;
}

// ---------------- token attention: Z = softmax(mask(S G S^T)) S ----------------
__global__ __launch_bounds__(256) void ktoken(const float* __restrict__ x,
                                              const u16* __restrict__ Gbf,
                                              u16* __restrict__ Z) {
  __shared__ float Ss[4 * 512];            // 8 KB
  __shared__ __align__(16) u16 Gs[16384];  // 32 KB [c][c2]
  int tid = threadIdx.x;
  int wave = tid >> 6, lane = tid & 63;
  int tok = blockIdx.x * 4 + wave;
  char* GsC = (char*)Gs;
#pragma unroll
  for (int it = 0; it < 8; ++it)
    gload16(Gbf + (size_t)(it * 256 + tid) * 8, GsC + it * 4096 + wave * 1024);
  {
    const float4* xs = (const float4*)(x + (size_t)tok * 512);
    float4* sw = (float4*)(Ss + wave * 512);
    sw[lane] = xs[lane];
    sw[64 + lane] = xs[64 + lane];
  }
  __syncthreads();  // G staged (vmcnt drained) + S visible

  const float* Sw = Ss + wave * 512;
  const u32* Grow = (const u32*)Gs;
  float a[4][2] = {{0.f, 0.f}, {0.f, 0.f}, {0.f, 0.f}, {0.f, 0.f}};
#pragma unroll 4
  for (int c = 0; c < 128; ++c) {
    u32 g2 = Grow[c * 64 + lane];
    float glo = __uint_as_float(g2 << 16);
    float ghi = __uint_as_float(g2 & 0xFFFF0000u);
    float s0 = Sw[c], s1 = Sw[128 + c], s2 = Sw[256 + c], s3 = Sw[384 + c];
    a[0][0] += s0 * glo; a[0][1] += s0 * ghi;
    a[1][0] += s1 * glo; a[1][1] += s1 * ghi;
    a[2][0] += s2 * glo; a[2][1] += s2 * ghi;
    a[3][0] += s3 * glo; a[3][1] += s3 * ghi;
  }
  float w[16];
#pragma unroll
  for (int j = 0; j < 4; ++j) {
    float sj0 = Sw[j * 128 + 2 * lane];
    float sj1 = Sw[j * 128 + 2 * lane + 1];
#pragma unroll
    for (int i = 0; i < 4; ++i)
      w[i * 4 + j] = a[i][0] * sj0 + a[i][1] * sj1;
  }
#pragma unroll
  for (int off = 1; off < 64; off <<= 1)
#pragma unroll
    for (int k = 0; k < 16; ++k) w[k] += __shfl_xor(w[k], off);
  float p[4][4];
#pragma unroll
  for (int i = 0; i < 4; ++i) {
    float m = w[i * 4];
    for (int j = 1; j <= i; ++j) m = fmaxf(m, w[i * 4 + j]);
    float s = 0.f;
    for (int j = 0; j <= i; ++j) { p[i][j] = __expf(w[i * 4 + j] - m); s += p[i][j]; }
    float inv = 1.f / s;
    for (int j = 0; j <= i; ++j) p[i][j] *= inv;
    for (int j = i + 1; j < 4; ++j) p[i][j] = 0.f;
  }
  int c = lane * 2;
  u32* zout = (u32*)(Z + (size_t)tok * 512);
#pragma unroll
  for (int i = 0; i < 4; ++i) {
    float z0 = 0.f, z1 = 0.f;
#pragma unroll
    for (int j = 0; j < 4; ++j) {
      z0 += p[i][j] * Sw[j * 128 + c];
      z1 += p[i][j] * Sw[j * 128 + c + 1];
    }
    zout[i * 64 + lane] = (u32)f2bf(z0) | ((u32)f2bf(z1) << 16);
  }
}

// ---------------- attn-out projection + bias + residual + LN1 -> X1 (bf16) ----------------
// AO layout: [0,16K) Z-tile (swizzled, gload16); [16K,48K) x f32 [16][512]
// (staged async, read only in stats phase); normalize phase reuses full 64K.
__global__ __launch_bounds__(512) void kattn(const u16* __restrict__ Z,
                                             const u16* __restrict__ WvpT,
                                             const float* __restrict__ bp,
                                             const float* __restrict__ x,
                                             const float* __restrict__ g1,
                                             const float* __restrict__ bln1,
                                             u16* __restrict__ X1) {
  __shared__ __align__(16) u16 AO[32768];
  __shared__ float rsum[64 * 4];
  __shared__ float rsq[64 * 4];
  __shared__ float mus[64];
  __shared__ float rss[64];
  char* smem = (char*)AO;
  int tid = threadIdx.x;
  int lane = tid & 63, wid = tid >> 6;
  int wm = wid >> 2, wnq = wid & 3;
  int lane_lo = lane & 15, lane_hi = lane >> 4;
  int m0 = blockIdx.x * 64;
  // stage Z (pre-swizzled source -> linear dest) and x (linear) via gload16
  {
    const u16* Zs = Z + (size_t)m0 * 128;
#pragma unroll
    for (int it = 0; it < 2; ++it) {
      int idx8 = it * 512 + tid;
      int row = idx8 >> 4, u = idx8 & 15;
      gload16(Zs + (size_t)row * 128 + ((u ^ (row & 7)) << 3), smem + idx8 * 16);
    }
    const float* xsrc = x + (size_t)(m0 >> 2) * 512;
#pragma unroll
    for (int it = 0; it < 4; ++it) {
      int idx = it * 512 + tid;
      gload16(xsrc + idx * 4, smem + 16384 + idx * 16);
    }
  }
  __syncthreads();
  f32x4 acc[2][8];
#pragma unroll
  for (int mi = 0; mi < 2; ++mi)
#pragma unroll
    for (int ni = 0; ni < 8; ++ni) acc[mi][ni] = (f32x4){0.f, 0.f, 0.f, 0.f};
#pragma unroll
  for (int ks = 0; ks < 4; ++ks) {
    bf16x8 af[2];
#pragma unroll
    for (int mi = 0; mi < 2; ++mi) {
      int row = wm * 32 + mi * 16 + lane_lo;
      int byte = (row * 256 + (ks * 32 + lane_hi * 8) * 2) ^ ((row & 7) << 4);
      af[mi] = *(const bf16x8*)(smem + byte);
    }
#pragma unroll
    for (int ni = 0; ni < 8; ++ni) {
      int n = wnq * 128 + ni * 16 + lane_lo;
      bf16x8 bfr = *(const bf16x8*)(WvpT + (size_t)n * 128 + ks * 32 + lane_hi * 8);
#pragma unroll
      for (int mi = 0; mi < 2; ++mi)
        acc[mi][ni] = __builtin_amdgcn_mfma_f32_16x16x32_bf16(af[mi], bfr, acc[mi][ni], 0, 0, 0);
    }
  }
  // hoisted per-lane constants
  float bpv[8], g1v[8], blv[8];
#pragma unroll
  for (int ni = 0; ni < 8; ++ni) {
    int col = wnq * 128 + ni * 16 + lane_lo;
    bpv[ni] = bp[col]; g1v[ni] = g1[col]; blv[ni] = bln1[col];
  }
  const float* xs = (const float*)(smem + 16384);
#pragma unroll
  for (int mi = 0; mi < 2; ++mi) {
#pragma unroll
    for (int j = 0; j < 4; ++j) {
      int rl = wm * 32 + mi * 16 + lane_hi * 4 + j;
      int tl = wm * 8 + mi * 4 + lane_hi;  // token_local = rl>>2
      float s = 0.f, q = 0.f;
#pragma unroll
      for (int ni = 0; ni < 8; ++ni) {
        int col = wnq * 128 + ni * 16 + lane_lo;
        float val = acc[mi][ni][j] + bpv[ni] + xs[tl * 512 + col];
        acc[mi][ni][j] = val;
        s += val; q += val * val;
      }
#pragma unroll
      for (int off = 1; off < 16; off <<= 1) { s += __shfl_xor(s, off); q += __shfl_xor(q, off); }
      if (lane_lo == 0) { rsum[rl * 4 + wnq] = s; rsq[rl * 4 + wnq] = q; }
    }
  }
  __syncthreads();
  if (tid < 64) {
    float s = rsum[tid * 4] + rsum[tid * 4 + 1] + rsum[tid * 4 + 2] + rsum[tid * 4 + 3];
    float q = rsq[tid * 4] + rsq[tid * 4 + 1] + rsq[tid * 4 + 2] + rsq[tid * 4 + 3];
    float mu = s * (1.f / 512.f);
    float var = q * (1.f / 512.f) - mu * mu;
    mus[tid] = mu;
    rss[tid] = rsqrtf(var + 512.0f);
  }
  __syncthreads();
#pragma unroll
  for (int mi = 0; mi < 2; ++mi) {
#pragma unroll
    for (int j = 0; j < 4; ++j) {
      int rl = wm * 32 + mi * 16 + lane_hi * 4 + j;
      float mu = mus[rl], rs = rss[rl];
#pragma unroll
      for (int ni = 0; ni < 8; ++ni) {
        int col = wnq * 128 + ni * 16 + lane_lo;
        AO[rl * 512 + col] = f2bf((acc[mi][ni][j] - mu) * rs * g1v[ni] + blv[ni]);
      }
    }
  }
  __syncthreads();
  {
    bf16x8* dst = (bf16x8*)(X1 + (size_t)m0 * 512);
    const bf16x8* s8 = (const bf16x8*)AO;
#pragma unroll
    for (int it = 0; it < 8; ++it) dst[it * 512 + tid] = s8[it * 512 + tid];
  }
}

// ======== single-buffered m97-style GEMM core (r7: best for short-K kff1) ========
template<int KDIM>
__device__ __forceinline__ void gemm_core_sb(const u16* __restrict__ Ap,
                                             const u16* __restrict__ Bp,
                                             u16* Ab, u16* Bb,
                                             int wid, int lane, f32x4 acc[4][4]) {
  const int lane_lo = lane & 15, lane_hi = lane >> 4;
  const int wm = wid >> 1, wn = wid & 1;
  const int rl8 = lane >> 3, u8 = lane & 7;
  char* AbC = (char*)Ab;
  char* BbC = (char*)Bb;
  for (int k0 = 0; k0 < KDIM; k0 += 64) {
#pragma unroll
    for (int i = 0; i < 4; ++i) {
      int row = wid * 32 + i * 8 + rl8;
      int usw = u8 ^ (row & 7);
      size_t goff = (size_t)row * KDIM + k0 + usw * 8;
      gload16(Ap + goff, AbC + wid * 4096 + i * 1024);
      gload16(Bp + goff, BbC + wid * 4096 + i * 1024);
    }
    __syncthreads();
#pragma unroll
    for (int ks = 0; ks < 2; ++ks) {
      bf16x8 av[4], bv[4];
#pragma unroll
      for (int mi = 0; mi < 4; ++mi) {
        int row = wm * 64 + mi * 16 + lane_lo;
        int usw = (ks * 4 + lane_hi) ^ (row & 7);
        av[mi] = *(const bf16x8*)(AbC + row * 128 + usw * 16);
      }
#pragma unroll
      for (int ni = 0; ni < 4; ++ni) {
        int row = wn * 64 + ni * 16 + lane_lo;
        int usw = (ks * 4 + lane_hi) ^ (row & 7);
        bv[ni] = *(const bf16x8*)(BbC + row * 128 + usw * 16);
      }
#pragma unroll
      for (int mi = 0; mi < 4; ++mi)
#pragma unroll
        for (int ni = 0; ni < 4; ++ni)
          acc[mi][ni] = __builtin_amdgcn_mfma_f32_16x16x32_bf16(av[mi], bv[ni], acc[mi][ni], 0, 0, 0);
    }
    __syncthreads();
  }
}

// ======== 2-phase double-buffered core (r8: best for long-K, H-streaming kff2) ========
template<int KDIM>
__device__ __forceinline__ void gemm_core_db(const u16* __restrict__ Ap,
                                             const u16* __restrict__ Bp,
                                             u16* AbBase, u16* BbBase,
                                             int wid, int lane, f32x4 acc[4][4]) {
  const int lane_lo = lane & 15, lane_hi = lane >> 4;
  const int wm = wid >> 1, wn = wid & 1;
  const int rl8 = lane >> 3, u8 = lane & 7;

  auto stage = [&](int buf, int k0) {
    char* AbC = (char*)AbBase + buf * 16384;
    char* BbC = (char*)BbBase + buf * 16384;
#pragma unroll
    for (int i = 0; i < 4; ++i) {
      int row = wid * 32 + i * 8 + rl8;
      int usw = u8 ^ (row & 7);
      size_t goff = (size_t)row * KDIM + k0 + usw * 8;
      gload16(Ap + goff, AbC + wid * 4096 + i * 1024);
      gload16(Bp + goff, BbC + wid * 4096 + i * 1024);
    }
  };
  auto compute = [&](int buf) {
    char* AbC = (char*)AbBase + buf * 16384;
    char* BbC = (char*)BbBase + buf * 16384;
#pragma unroll
    for (int ks = 0; ks < 2; ++ks) {
      bf16x8 av[4], bv[4];
#pragma unroll
      for (int mi = 0; mi < 4; ++mi) {
        int row = wm * 64 + mi * 16 + lane_lo;
        int usw = (ks * 4 + lane_hi) ^ (row & 7);
        av[mi] = *(const bf16x8*)(AbC + row * 128 + usw * 16);
      }
#pragma unroll
      for (int ni = 0; ni < 4; ++ni) {
        int row = wn * 64 + ni * 16 + lane_lo;
        int usw = (ks * 4 + lane_hi) ^ (row & 7);
        bv[ni] = *(const bf16x8*)(BbC + row * 128 + usw * 16);
      }
#pragma unroll
      for (int mi = 0; mi < 4; ++mi)
#pragma unroll
        for (int ni = 0; ni < 4; ++ni)
          acc[mi][ni] = __builtin_amdgcn_mfma_f32_16x16x32_bf16(av[mi], bv[ni], acc[mi][ni], 0, 0, 0);
    }
  };

  stage(0, 0);
  asm volatile("s_waitcnt vmcnt(0)" ::: "memory");
  __builtin_amdgcn_s_barrier();
  __builtin_amdgcn_sched_barrier(0);
  int cur = 0;
  for (int k0 = 64; k0 < KDIM; k0 += 64) {
    stage(cur ^ 1, k0);
    compute(cur);
    asm volatile("s_waitcnt vmcnt(0)" ::: "memory");
    __builtin_amdgcn_s_barrier();
    __builtin_amdgcn_sched_barrier(0);
    cur ^= 1;
  }
  compute(cur);
}

// FF1: H = gelu(X1 @ W1 + b1), K=512, N=2048 (16 n-blocks); r7 structure.
__global__ __launch_bounds__(256) void kff1(const u16* __restrict__ X1s,
                                            const u16* __restrict__ W1T,
                                            const float* __restrict__ b1v,
                                            u16* __restrict__ H) {
  __shared__ __align__(16) u16 Ab[8192];
  __shared__ __align__(16) u16 Bb[8192];
  int tid = threadIdx.x, lane = tid & 63, wid = tid >> 6;
  int nwg = gridDim.x, bid = blockIdx.x;
  int m128 = nwg >> 4;
  int xcd = bid & 7, idx = bid >> 3;
  int mb = xcd * (m128 >> 3) + (idx >> 4);
  int nb = idx & 15;
  const u16* Ap = X1s + (size_t)mb * 128 * 512;
  const u16* Bp = W1T + (size_t)nb * 128 * 512;
  f32x4 acc[4][4];
#pragma unroll
  for (int mi = 0; mi < 4; ++mi)
#pragma unroll
    for (int ni = 0; ni < 4; ++ni) acc[mi][ni] = (f32x4){0.f, 0.f, 0.f, 0.f};
  gemm_core_sb<512>(Ap, Bp, Ab, Bb, wid, lane, acc);
  int lane_lo = lane & 15, lane_hi = lane >> 4;
  int wm = wid >> 1, wn = wid & 1;
  float bvals[4];
#pragma unroll
  for (int ni = 0; ni < 4; ++ni) bvals[ni] = b1v[nb * 128 + wn * 64 + ni * 16 + lane_lo];
  int colb = nb * 128 + (wn * 16 + lane_lo) * 4;
#pragma unroll
  for (int mi = 0; mi < 4; ++mi)
#pragma unroll
    for (int j = 0; j < 4; ++j) {
      int rl = wm * 64 + mi * 16 + lane_hi * 4 + j;
      u16x4 pk;
#pragma unroll
      for (int ni = 0; ni < 4; ++ni)
        pk[ni] = f2bf(gelu_f(acc[mi][ni][j] + bvals[ni]));
      *(u16x4*)(H + ((size_t)mb * 128 + rl) * 2048 + colb) = pk;
    }
}

// FF2: y = H @ W2 + b2 + X1, written bf16 IN-PLACE over X1 (per-element
// read-then-write by the same thread; X1 has no other consumers after this).
__global__ __launch_bounds__(256) void kff2(const u16* __restrict__ H,
                                            const u16* __restrict__ W2T,
                                            const float* __restrict__ b2v,
                                            u16* __restrict__ X1y) {
  __shared__ __align__(16) u16 Ab[16384];
  __shared__ __align__(16) u16 Bb[16384];
  int tid = threadIdx.x, lane = tid & 63, wid = tid >> 6;
  int nwg = gridDim.x, bid = blockIdx.x;
  int m128 = nwg >> 2;
  int xcd = bid & 7, idx = bid >> 3;
  int mb = xcd * (m128 >> 3) + (idx >> 2);
  int nb = idx & 3;
  const u16* Ap = H + (size_t)mb * 128 * 2048;
  const u16* Bp = W2T + (size_t)nb * 128 * 2048;
  f32x4 acc[4][4];
#pragma unroll
  for (int mi = 0; mi < 4; ++mi)
#pragma unroll
    for (int ni = 0; ni < 4; ++ni) acc[mi][ni] = (f32x4){0.f, 0.f, 0.f, 0.f};
  gemm_core_db<2048>(Ap, Bp, Ab, Bb, wid, lane, acc);
  int lane_lo = lane & 15, lane_hi = lane >> 4;
  int wm = wid >> 1, wn = wid & 1;
#pragma unroll
  for (int mi = 0; mi < 4; ++mi)
#pragma unroll
    for (int j = 0; j < 4; ++j) {
      int rl = wm * 64 + mi * 16 + lane_hi * 4 + j;
      size_t row = (size_t)mb * 128 + rl;
      u16* xrow = X1y + row * 512 + nb * 128;
#pragma unroll
      for (int ni = 0; ni < 4; ++ni) {
        int col = wn * 64 + ni * 16 + lane_lo;
        float val = acc[mi][ni][j] + b2v[nb * 128 + col] + bf2f(xrow[col]);
        xrow[col] = f2bf(val);
      }
    }
}

// LN2: out = LN(y) where y is bf16 (in X1 buffer). One wave per row.
__global__ __launch_bounds__(512) void kln2(const u16* __restrict__ Y,
                                            const float* __restrict__ g2,
                                            const float* __restrict__ bb2,
                                            float* __restrict__ out) {
  int wid = threadIdx.x >> 6, lane = threadIdx.x & 63;
  size_t row = (size_t)blockIdx.x * 8 + wid;
  u16x8 v = *(const u16x8*)(Y + row * 512 + lane * 8);
  float f[8];
  float s = 0.f, q = 0.f;
#pragma unroll
  for (int k = 0; k < 8; ++k) {
    f[k] = bf2f(v[k]);
    s += f[k]; q += f[k] * f[k];
  }
#pragma unroll
  for (int off = 1; off < 64; off <<= 1) { s += __shfl_xor(s, off); q += __shfl_xor(q, off); }
  float mu = s * (1.f / 512.f);
  float rs = rsqrtf(q * (1.f / 512.f) - mu * mu + 512.0f);
  float4 ga = *(const float4*)(g2 + lane * 8);
  float4 gb = *(const float4*)(g2 + lane * 8 + 4);
  float4 ba = *(const float4*)(bb2 + lane * 8);
  float4 bb = *(const float4*)(bb2 + lane * 8 + 4);
  float4 o0, o1;
  o0.x = (f[0] - mu) * rs * ga.x + ba.x;
  o0.y = (f[1] - mu) * rs * ga.y + ba.y;
  o0.z = (f[2] - mu) * rs * ga.z + ba.z;
  o0.w = (f[3] - mu) * rs * ga.w + ba.w;
  o1.x = (f[4] - mu) * rs * gb.x + bb.x;
  o1.y = (f[5] - mu) * rs * gb.y + bb.y;
  o1.z = (f[6] - mu) * rs * gb.z + bb.z;
  o1.w = (f[7] - mu) * rs * gb.w + bb.w;
  float* orow = out + row * 512 + lane * 8;
  *(float4*)orow = o0;
  *(float4*)(orow + 4) = o1;
}

extern "C" void kernel_launch(void* const* d_in, const int* in_sizes, int n_in,
                              void* d_out, int out_size, void* d_ws, size_t ws_size,
                              hipStream_t stream) {
  const float* x   = (const float*)d_in[0];
  const float* Wq  = (const float*)d_in[1];
  const float* Wk  = (const float*)d_in[2];
  const float* Wv  = (const float*)d_in[3];
  const float* Wp  = (const float*)d_in[4];
  const float* bp  = (const float*)d_in[5];
  const float* W1  = (const float*)d_in[6];
  const float* b1  = (const float*)d_in[7];
  const float* W2  = (const float*)d_in[8];
  const float* b2  = (const float*)d_in[9];
  const float* g1  = (const float*)d_in[10];
  const float* bb1 = (const float*)d_in[11];
  const float* g2  = (const float*)d_in[12];
  const float* bb2 = (const float*)d_in[13];
  float* out = (float*)d_out;

  char* ws = (char*)d_ws;
  u16* Gbf  = (u16*)ws;                      // 32KB (region reserved 256KB)
  u16* WvpT = (u16*)(ws + (256 << 10));      // 128KB
  u16* W1T  = (u16*)(ws + (1 << 20));        // 2MB
  u16* W2T  = (u16*)(ws + (3 << 20));        // 2MB
  u16* Z    = (u16*)(ws + (5 << 20));        // 16MB
  u16* X1   = (u16*)(ws + (21 << 20));       // 64MB (becomes y bf16 after kff2)
  u16* H    = (u16*)(ws + (85ull << 20));    // H slice region

  hipLaunchKernelGGL(kprep_G,   dim3(64),        dim3(256), 0, stream, Wq, Wk, Gbf);
  hipLaunchKernelGGL(kprep_Wvp, dim3(256),       dim3(256), 0, stream, Wv, Wp, WvpT);
  hipLaunchKernelGGL(kprep_W1T, dim3(32, 8),     dim3(256), 0, stream, W1, W1T);
  hipLaunchKernelGGL(kprep_W2T, dim3(32, 8),     dim3(256), 0, stream, W2, W2T);
  hipLaunchKernelGGL(ktoken,    dim3(4096),      dim3(256), 0, stream, x, Gbf, Z);
  hipLaunchKernelGGL(kattn,     dim3(1024),      dim3(512), 0, stream, Z, WvpT, bp, x, g1, bb1, X1);

  // S>=4 so each H slice (<=64MB) is L3-resident between kff1 and kff2
  const size_t hbase = 85ull << 20;
  int S = 64;
  for (int c = 4; c <= 64; c <<= 1) {
    if (hbase + (268435456ull / (size_t)c) <= ws_size) { S = c; break; }
  }
  int Ms = MROWS / S;   // 16384 rows at S=4
  for (int s = 0; s < S; ++s) {
    const u16* x1s = X1 + (size_t)s * Ms * 512;
    hipLaunchKernelGGL(kff1, dim3((Ms / 128) * 16), dim3(256), 0, stream, x1s, W1T, b1, H);
    hipLaunchKernelGGL(kff2, dim3((Ms / 128) * 4),  dim3(256), 0, stream, H, W2T, b2,
                       X1 + (size_t)s * Ms * 512);
  }
  hipLaunchKernelGGL(kln2, dim3(8192), dim3(512), 0, stream, X1, g2, bb2, out);
}

// Round 14
// 576.095 us; speedup vs baseline: 1.3522x; 1.0356x over previous
//
#include <hip/hip_runtime.h>
#include <hip/hip_bf16.h>
#include <math.h>

typedef __bf16 bf16x8 __attribute__((ext_vector_type(8)));
typedef float f32x4 __attribute__((ext_vector_type(4)));
typedef unsigned short u16;
typedef unsigned int u32;
typedef u16 u16x4 __attribute__((ext_vector_type(4)));
typedef u16 u16x8 __attribute__((ext_vector_type(8)));

#define TOKENS 16384
#define MROWS  65536

__device__ __forceinline__ u16 f2bf(float f) {
  union { __hip_bfloat16 h; u16 u; } c;
  c.h = __float2bfloat16(f);
  return c.u;
}
__device__ __forceinline__ float bf2f(u16 u) {
  union { u16 u; __hip_bfloat16 h; } c;
  c.u = u;
  return __bfloat162float(c.h);
}
// sigmoid-form gelu (validated r6-r13, absmax 6.1e-5)
__device__ __forceinline__ float gelu_f(float u) {
  float y2 = u * fmaf(0.07135481283f, u * u, 1.595769122f);
  float e = __expf(-y2);
  return u / (1.f + e);
}
// async global->LDS, 16B per lane; LDS dest is wave-uniform base + lane*16
__device__ __forceinline__ void gload16(const void* g, void* l) {
  __builtin_amdgcn_global_load_lds(
      (const __attribute__((address_space(1))) void*)g,
      (__attribute__((address_space(3))) void*)l, 16, 0, 0);
}

// ---------------- prep kernels ----------------
// Gbf[c][c2] = bf16( (1/sqrt(512)) * sum_d Wq[c][d]*Wk[c2][d] )   (128x128)
__global__ void kprep_G(const float* __restrict__ Wq, const float* __restrict__ Wk,
                        u16* __restrict__ Gbf) {
  int id = blockIdx.x * 256 + threadIdx.x;  // 16384
  int c = id >> 7, c2 = id & 127;
  const float4* a = (const float4*)(Wq + (size_t)c * 512);
  const float4* b = (const float4*)(Wk + (size_t)c2 * 512);
  float s = 0.f;
#pragma unroll 8
  for (int i = 0; i < 128; ++i) {
    float4 xa = a[i], yb = b[i];
    s += xa.x * yb.x + xa.y * yb.y + xa.z * yb.z + xa.w * yb.w;
  }
  Gbf[id] = f2bf(s * 0.044194173824159216f);
}

__global__ void kprep_Wvp(const float* __restrict__ Wv, const float* __restrict__ Wp,
                          u16* __restrict__ WvpT) {
  int id = blockIdx.x * 256 + threadIdx.x;  // 65536 : e*128+c
  int e = id >> 7, c = id & 127;
  float s = 0.f;
#pragma unroll 4
  for (int d = 0; d < 512; ++d) s += Wv[(size_t)c * 512 + d] * Wp[(size_t)d * 512 + e];
  WvpT[id] = f2bf(s);
}

// W1T[f][e] = bf16(W1[e][f]) via 64x64 LDS tile: coalesced reads AND writes.
__global__ __launch_bounds__(256) void kprep_W1T(const float* __restrict__ W1,
                                                 u16* __restrict__ W1T) {
  __shared__ u16 Lt[64][72];  // [e_local][f_local]
  int tid = threadIdx.x;
  int bf = blockIdx.x, be = blockIdx.y;
#pragma unroll
  for (int rnd = 0; rnd < 4; ++rnd) {
    int r = rnd * 16 + (tid >> 4);          // e_local
    int f4 = (tid & 15) * 4;                // f_local
    float4 v = *(const float4*)(W1 + (size_t)(be * 64 + r) * 2048 + bf * 64 + f4);
    Lt[r][f4] = f2bf(v.x); Lt[r][f4 + 1] = f2bf(v.y);
    Lt[r][f4 + 2] = f2bf(v.z); Lt[r][f4 + 3] = f2bf(v.w);
  }
  __syncthreads();
  int fl = tid >> 2, eg = (tid & 3) * 16;
  u16x8 o0, o1;
#pragma unroll
  for (int q = 0; q < 8; ++q) { o0[q] = Lt[eg + q][fl]; o1[q] = Lt[eg + 8 + q][fl]; }
  u16* dst = W1T + (size_t)(bf * 64 + fl) * 512 + be * 64 + eg;
  *(u16x8*)dst = o0;
  *(u16x8*)(dst + 8) = o1;
}

// W2T[e][fst] = bf16(W2[f_true][e]), H-column permutation per 128-block (validated).
__global__ __launch_bounds__(256) void kprep_W2T(const float* __restrict__ W2,
                                                 u16* __restrict__ W2T) {
  __shared__ u16 Lt[64][72];  // [f_local][e_local]
  int tid = threadIdx.x;
  int bf = blockIdx.x, be = blockIdx.y;
#pragma unroll
  for (int rnd = 0; rnd < 4; ++rnd) {
    int r = rnd * 16 + (tid >> 4);          // f_local
    int e4 = (tid & 15) * 4;                // e_local
    float4 v = *(const float4*)(W2 + (size_t)(bf * 64 + r) * 512 + be * 64 + e4);
    Lt[r][e4] = f2bf(v.x); Lt[r][e4 + 1] = f2bf(v.y);
    Lt[r][e4 + 2] = f2bf(v.z); Lt[r][e4 + 3] = f2bf(v.w);
  }
  __syncthreads();
  int aa = bf & 1, fb = bf >> 1;
  int el = tid >> 2, g = tid & 3;
  u16x8 o0, o1;
#pragma unroll
  for (int q = 0; q < 8; ++q) {
    int fs0 = g * 16 + q, fs1 = g * 16 + 8 + q;
    o0[q] = Lt[(fs0 & 3) * 16 + ((fs0 >> 2) & 15)][el];
    o1[q] = Lt[(fs1 & 3) * 16 + ((fs1 >> 2) & 15)][el];
  }
  u16* dst = W2T + (size_t)(be * 64 + el) * 2048 + fb * 128 + aa * 64 + g * 16;
  *(u16x8*)dst = o0;
  *(u16x8*)(dst + 8) = o1;
}

// ---------------- token attention: Z = softmax(mask(S G S^T)) S ----------------
__global__ __launch_bounds__(256) void ktoken(const float* __restrict__ x,
                                              const u16* __restrict__ Gbf,
                                              u16* __restrict__ Z) {
  __shared__ float Ss[4 * 512];            // 8 KB
  __shared__ __align__(16) u16 Gs[16384];  // 32 KB [c][c2]
  int tid = threadIdx.x;
  int wave = tid >> 6, lane = tid & 63;
  int tok = blockIdx.x * 4 + wave;
  char* GsC = (char*)Gs;
#pragma unroll
  for (int it = 0; it < 8; ++it)
    gload16(Gbf + (size_t)(it * 256 + tid) * 8, GsC + it * 4096 + wave * 1024);
  {
    const float4* xs = (const float4*)(x + (size_t)tok * 512);
    float4* sw = (float4*)(Ss + wave * 512);
    sw[lane] = xs[lane];
    sw[64 + lane] = xs[64 + lane];
  }
  __syncthreads();  // G staged (vmcnt drained) + S visible

  const float* Sw = Ss + wave * 512;
  const u32* Grow = (const u32*)Gs;
  float a[4][2] = {{0.f, 0.f}, {0.f, 0.f}, {0.f, 0.f}, {0.f, 0.f}};
#pragma unroll 4
  for (int c = 0; c < 128; ++c) {
    u32 g2 = Grow[c * 64 + lane];
    float glo = __uint_as_float(g2 << 16);
    float ghi = __uint_as_float(g2 & 0xFFFF0000u);
    float s0 = Sw[c], s1 = Sw[128 + c], s2 = Sw[256 + c], s3 = Sw[384 + c];
    a[0][0] += s0 * glo; a[0][1] += s0 * ghi;
    a[1][0] += s1 * glo; a[1][1] += s1 * ghi;
    a[2][0] += s2 * glo; a[2][1] += s2 * ghi;
    a[3][0] += s3 * glo; a[3][1] += s3 * ghi;
  }
  float w[16];
#pragma unroll
  for (int j = 0; j < 4; ++j) {
    float sj0 = Sw[j * 128 + 2 * lane];
    float sj1 = Sw[j * 128 + 2 * lane + 1];
#pragma unroll
    for (int i = 0; i < 4; ++i)
      w[i * 4 + j] = a[i][0] * sj0 + a[i][1] * sj1;
  }
#pragma unroll
  for (int off = 1; off < 64; off <<= 1)
#pragma unroll
    for (int k = 0; k < 16; ++k) w[k] += __shfl_xor(w[k], off);
  float p[4][4];
#pragma unroll
  for (int i = 0; i < 4; ++i) {
    float m = w[i * 4];
    for (int j = 1; j <= i; ++j) m = fmaxf(m, w[i * 4 + j]);
    float s = 0.f;
    for (int j = 0; j <= i; ++j) { p[i][j] = __expf(w[i * 4 + j] - m); s += p[i][j]; }
    float inv = 1.f / s;
    for (int j = 0; j <= i; ++j) p[i][j] *= inv;
    for (int j = i + 1; j < 4; ++j) p[i][j] = 0.f;
  }
  int c = lane * 2;
  u32* zout = (u32*)(Z + (size_t)tok * 512);
#pragma unroll
  for (int i = 0; i < 4; ++i) {
    float z0 = 0.f, z1 = 0.f;
#pragma unroll
    for (int j = 0; j < 4; ++j) {
      z0 += p[i][j] * Sw[j * 128 + c];
      z1 += p[i][j] * Sw[j * 128 + c + 1];
    }
    zout[i * 64 + lane] = (u32)f2bf(z0) | ((u32)f2bf(z1) << 16);
  }
}

// ---------------- attn-out projection + bias + residual + LN1 -> X1 (bf16) ----------------
__global__ __launch_bounds__(512) void kattn(const u16* __restrict__ Z,
                                             const u16* __restrict__ WvpT,
                                             const float* __restrict__ bp,
                                             const float* __restrict__ x,
                                             const float* __restrict__ g1,
                                             const float* __restrict__ bln1,
                                             u16* __restrict__ X1) {
  __shared__ __align__(16) u16 AO[32768];
  __shared__ float rsum[64 * 4];
  __shared__ float rsq[64 * 4];
  __shared__ float mus[64];
  __shared__ float rss[64];
  char* smem = (char*)AO;
  int tid = threadIdx.x;
  int lane = tid & 63, wid = tid >> 6;
  int wm = wid >> 2, wnq = wid & 3;
  int lane_lo = lane & 15, lane_hi = lane >> 4;
  int m0 = blockIdx.x * 64;
  {
    const u16* Zs = Z + (size_t)m0 * 128;
#pragma unroll
    for (int it = 0; it < 2; ++it) {
      int idx8 = it * 512 + tid;
      int row = idx8 >> 4, u = idx8 & 15;
      gload16(Zs + (size_t)row * 128 + ((u ^ (row & 7)) << 3), smem + idx8 * 16);
    }
    const float* xsrc = x + (size_t)(m0 >> 2) * 512;
#pragma unroll
    for (int it = 0; it < 4; ++it) {
      int idx = it * 512 + tid;
      gload16(xsrc + idx * 4, smem + 16384 + idx * 16);
    }
  }
  __syncthreads();
  f32x4 acc[2][8];
#pragma unroll
  for (int mi = 0; mi < 2; ++mi)
#pragma unroll
    for (int ni = 0; ni < 8; ++ni) acc[mi][ni] = (f32x4){0.f, 0.f, 0.f, 0.f};
#pragma unroll
  for (int ks = 0; ks < 4; ++ks) {
    bf16x8 af[2];
#pragma unroll
    for (int mi = 0; mi < 2; ++mi) {
      int row = wm * 32 + mi * 16 + lane_lo;
      int byte = (row * 256 + (ks * 32 + lane_hi * 8) * 2) ^ ((row & 7) << 4);
      af[mi] = *(const bf16x8*)(smem + byte);
    }
#pragma unroll
    for (int ni = 0; ni < 8; ++ni) {
      int n = wnq * 128 + ni * 16 + lane_lo;
      bf16x8 bfr = *(const bf16x8*)(WvpT + (size_t)n * 128 + ks * 32 + lane_hi * 8);
#pragma unroll
      for (int mi = 0; mi < 2; ++mi)
        acc[mi][ni] = __builtin_amdgcn_mfma_f32_16x16x32_bf16(af[mi], bfr, acc[mi][ni], 0, 0, 0);
    }
  }
  float bpv[8], g1v[8], blv[8];
#pragma unroll
  for (int ni = 0; ni < 8; ++ni) {
    int col = wnq * 128 + ni * 16 + lane_lo;
    bpv[ni] = bp[col]; g1v[ni] = g1[col]; blv[ni] = bln1[col];
  }
  const float* xs = (const float*)(smem + 16384);
#pragma unroll
  for (int mi = 0; mi < 2; ++mi) {
#pragma unroll
    for (int j = 0; j < 4; ++j) {
      int rl = wm * 32 + mi * 16 + lane_hi * 4 + j;
      int tl = wm * 8 + mi * 4 + lane_hi;
      float s = 0.f, q = 0.f;
#pragma unroll
      for (int ni = 0; ni < 8; ++ni) {
        int col = wnq * 128 + ni * 16 + lane_lo;
        float val = acc[mi][ni][j] + bpv[ni] + xs[tl * 512 + col];
        acc[mi][ni][j] = val;
        s += val; q += val * val;
      }
#pragma unroll
      for (int off = 1; off < 16; off <<= 1) { s += __shfl_xor(s, off); q += __shfl_xor(q, off); }
      if (lane_lo == 0) { rsum[rl * 4 + wnq] = s; rsq[rl * 4 + wnq] = q; }
    }
  }
  __syncthreads();
  if (tid < 64) {
    float s = rsum[tid * 4] + rsum[tid * 4 + 1] + rsum[tid * 4 + 2] + rsum[tid * 4 + 3];
    float q = rsq[tid * 4] + rsq[tid * 4 + 1] + rsq[tid * 4 + 2] + rsq[tid * 4 + 3];
    float mu = s * (1.f / 512.f);
    float var = q * (1.f / 512.f) - mu * mu;
    mus[tid] = mu;
    rss[tid] = rsqrtf(var + 512.0f);
  }
  __syncthreads();
#pragma unroll
  for (int mi = 0; mi < 2; ++mi) {
#pragma unroll
    for (int j = 0; j < 4; ++j) {
      int rl = wm * 32 + mi * 16 + lane_hi * 4 + j;
      float mu = mus[rl], rs = rss[rl];
#pragma unroll
      for (int ni = 0; ni < 8; ++ni) {
        int col = wnq * 128 + ni * 16 + lane_lo;
        AO[rl * 512 + col] = f2bf((acc[mi][ni][j] - mu) * rs * g1v[ni] + blv[ni]);
      }
    }
  }
  __syncthreads();
  {
    bf16x8* dst = (bf16x8*)(X1 + (size_t)m0 * 512);
    const bf16x8* s8 = (const bf16x8*)AO;
#pragma unroll
    for (int it = 0; it < 8; ++it) dst[it * 512 + tid] = s8[it * 512 + tid];
  }
}

// ======== 2-phase double-buffered core (r8: best for long-K, H-streaming kff2) ========
template<int KDIM>
__device__ __forceinline__ void gemm_core_db(const u16* __restrict__ Ap,
                                             const u16* __restrict__ Bp,
                                             u16* AbBase, u16* BbBase,
                                             int wid, int lane, f32x4 acc[4][4]) {
  const int lane_lo = lane & 15, lane_hi = lane >> 4;
  const int wm = wid >> 1, wn = wid & 1;
  const int rl8 = lane >> 3, u8 = lane & 7;

  auto stage = [&](int buf, int k0) {
    char* AbC = (char*)AbBase + buf * 16384;
    char* BbC = (char*)BbBase + buf * 16384;
#pragma unroll
    for (int i = 0; i < 4; ++i) {
      int row = wid * 32 + i * 8 + rl8;
      int usw = u8 ^ (row & 7);
      size_t goff = (size_t)row * KDIM + k0 + usw * 8;
      gload16(Ap + goff, AbC + wid * 4096 + i * 1024);
      gload16(Bp + goff, BbC + wid * 4096 + i * 1024);
    }
  };
  auto compute = [&](int buf) {
    char* AbC = (char*)AbBase + buf * 16384;
    char* BbC = (char*)BbBase + buf * 16384;
#pragma unroll
    for (int ks = 0; ks < 2; ++ks) {
      bf16x8 av[4], bv[4];
#pragma unroll
      for (int mi = 0; mi < 4; ++mi) {
        int row = wm * 64 + mi * 16 + lane_lo;
        int usw = (ks * 4 + lane_hi) ^ (row & 7);
        av[mi] = *(const bf16x8*)(AbC + row * 128 + usw * 16);
      }
#pragma unroll
      for (int ni = 0; ni < 4; ++ni) {
        int row = wn * 64 + ni * 16 + lane_lo;
        int usw = (ks * 4 + lane_hi) ^ (row & 7);
        bv[ni] = *(const bf16x8*)(BbC + row * 128 + usw * 16);
      }
#pragma unroll
      for (int mi = 0; mi < 4; ++mi)
#pragma unroll
        for (int ni = 0; ni < 4; ++ni)
          acc[mi][ni] = __builtin_amdgcn_mfma_f32_16x16x32_bf16(av[mi], bv[ni], acc[mi][ni], 0, 0, 0);
    }
  };

  stage(0, 0);
  asm volatile("s_waitcnt vmcnt(0)" ::: "memory");
  __builtin_amdgcn_s_barrier();
  __builtin_amdgcn_sched_barrier(0);
  int cur = 0;
  for (int k0 = 64; k0 < KDIM; k0 += 64) {
    stage(cur ^ 1, k0);
    compute(cur);
    asm volatile("s_waitcnt vmcnt(0)" ::: "memory");
    __builtin_amdgcn_s_barrier();
    __builtin_amdgcn_sched_barrier(0);
    cur ^= 1;
  }
  compute(cur);
}

// FF1 v3: 256x128 tile, 512 threads (8 waves 4M x 2N, wave tile 64x64).
// LDS: A[256][64] 32KB + B[128][64] 16KB = 48KB -> 3 blocks/CU.
// Doubles MFMA per barrier vs 128^2 (stall amortized); identical wn/ni/lane_lo
// output mapping -> H permutation & kprep_W2T unchanged (validated r7-r13).
__global__ __launch_bounds__(512) void kff1(const u16* __restrict__ X1s,
                                            const u16* __restrict__ W1T,
                                            const float* __restrict__ b1v,
                                            u16* __restrict__ H) {
  __shared__ __align__(16) u16 Ab[16384];  // 32KB [256][64]
  __shared__ __align__(16) u16 Bb[8192];   // 16KB [128][64]
  char* AbC = (char*)Ab;
  char* BbC = (char*)Bb;
  int tid = threadIdx.x, lane = tid & 63, wid = tid >> 6;
  int lane_lo = lane & 15, lane_hi = lane >> 4;
  int wm = wid >> 1, wn = wid & 1;
  int rl8 = lane >> 3, u8 = lane & 7;
  int nwg = gridDim.x, bid = blockIdx.x;
  int m256 = nwg >> 4;                 // blocks along M (Ms/256)
  int xcd = bid & 7, idx = bid >> 3;
  int mb = xcd * (m256 >> 3) + (idx >> 4);
  int nb = idx & 15;
  const u16* Ap = X1s + (size_t)mb * 256 * 512;
  const u16* Bp = W1T + (size_t)nb * 128 * 512;
  f32x4 acc[4][4];
#pragma unroll
  for (int mi = 0; mi < 4; ++mi)
#pragma unroll
    for (int ni = 0; ni < 4; ++ni) acc[mi][ni] = (f32x4){0.f, 0.f, 0.f, 0.f};

  for (int k0 = 0; k0 < 512; k0 += 64) {
    // stage A: 256 rows, 32/wave (4 insts); B: 128 rows, 16/wave (2 insts)
#pragma unroll
    for (int i = 0; i < 4; ++i) {
      int row = wid * 32 + i * 8 + rl8;
      int usw = u8 ^ (row & 7);
      gload16(Ap + (size_t)row * 512 + k0 + usw * 8, AbC + wid * 4096 + i * 1024);
    }
#pragma unroll
    for (int i = 0; i < 2; ++i) {
      int row = wid * 16 + i * 8 + rl8;
      int usw = u8 ^ (row & 7);
      gload16(Bp + (size_t)row * 512 + k0 + usw * 8, BbC + wid * 2048 + i * 1024);
    }
    __syncthreads();
#pragma unroll
    for (int ks = 0; ks < 2; ++ks) {
      bf16x8 av[4], bv[4];
#pragma unroll
      for (int mi = 0; mi < 4; ++mi) {
        int row = wm * 64 + mi * 16 + lane_lo;
        int usw = (ks * 4 + lane_hi) ^ (row & 7);
        av[mi] = *(const bf16x8*)(AbC + row * 128 + usw * 16);
      }
#pragma unroll
      for (int ni = 0; ni < 4; ++ni) {
        int row = wn * 64 + ni * 16 + lane_lo;
        int usw = (ks * 4 + lane_hi) ^ (row & 7);
        bv[ni] = *(const bf16x8*)(BbC + row * 128 + usw * 16);
      }
#pragma unroll
      for (int mi = 0; mi < 4; ++mi)
#pragma unroll
        for (int ni = 0; ni < 4; ++ni)
          acc[mi][ni] = __builtin_amdgcn_mfma_f32_16x16x32_bf16(av[mi], bv[ni], acc[mi][ni], 0, 0, 0);
    }
    __syncthreads();
  }
  float bvals[4];
#pragma unroll
  for (int ni = 0; ni < 4; ++ni) bvals[ni] = b1v[nb * 128 + wn * 64 + ni * 16 + lane_lo];
  int colb = nb * 128 + (wn * 16 + lane_lo) * 4;
#pragma unroll
  for (int mi = 0; mi < 4; ++mi)
#pragma unroll
    for (int j = 0; j < 4; ++j) {
      int rl = wm * 64 + mi * 16 + lane_hi * 4 + j;
      u16x4 pk;
#pragma unroll
      for (int ni = 0; ni < 4; ++ni)
        pk[ni] = f2bf(gelu_f(acc[mi][ni][j] + bvals[ni]));
      *(u16x4*)(H + ((size_t)mb * 256 + rl) * 2048 + colb) = pk;
    }
}

// FF2: y = H @ W2 + b2 + X1, written bf16 IN-PLACE over X1.
__global__ __launch_bounds__(256) void kff2(const u16* __restrict__ H,
                                            const u16* __restrict__ W2T,
                                            const float* __restrict__ b2v,
                                            u16* __restrict__ X1y) {
  __shared__ __align__(16) u16 Ab[16384];
  __shared__ __align__(16) u16 Bb[16384];
  int tid = threadIdx.x, lane = tid & 63, wid = tid >> 6;
  int nwg = gridDim.x, bid = blockIdx.x;
  int m128 = nwg >> 2;
  int xcd = bid & 7, idx = bid >> 3;
  int mb = xcd * (m128 >> 3) + (idx >> 2);
  int nb = idx & 3;
  const u16* Ap = H + (size_t)mb * 128 * 2048;
  const u16* Bp = W2T + (size_t)nb * 128 * 2048;
  f32x4 acc[4][4];
#pragma unroll
  for (int mi = 0; mi < 4; ++mi)
#pragma unroll
    for (int ni = 0; ni < 4; ++ni) acc[mi][ni] = (f32x4){0.f, 0.f, 0.f, 0.f};
  gemm_core_db<2048>(Ap, Bp, Ab, Bb, wid, lane, acc);
  int lane_lo = lane & 15, lane_hi = lane >> 4;
  int wm = wid >> 1, wn = wid & 1;
#pragma unroll
  for (int mi = 0; mi < 4; ++mi)
#pragma unroll
    for (int j = 0; j < 4; ++j) {
      int rl = wm * 64 + mi * 16 + lane_hi * 4 + j;
      size_t row = (size_t)mb * 128 + rl;
      u16* xrow = X1y + row * 512 + nb * 128;
#pragma unroll
      for (int ni = 0; ni < 4; ++ni) {
        int col = wn * 64 + ni * 16 + lane_lo;
        float val = acc[mi][ni][j] + b2v[nb * 128 + col] + bf2f(xrow[col]);
        xrow[col] = f2bf(val);
      }
    }
}

// LN2: out = LN(y) where y is bf16 (in X1 buffer). One wave per row.
__global__ __launch_bounds__(512) void kln2(const u16* __restrict__ Y,
                                            const float* __restrict__ g2,
                                            const float* __restrict__ bb2,
                                            float* __restrict__ out) {
  int wid = threadIdx.x >> 6, lane = threadIdx.x & 63;
  size_t row = (size_t)blockIdx.x * 8 + wid;
  u16x8 v = *(const u16x8*)(Y + row * 512 + lane * 8);
  float f[8];
  float s = 0.f, q = 0.f;
#pragma unroll
  for (int k = 0; k < 8; ++k) {
    f[k] = bf2f(v[k]);
    s += f[k]; q += f[k] * f[k];
  }
#pragma unroll
  for (int off = 1; off < 64; off <<= 1) { s += __shfl_xor(s, off); q += __shfl_xor(q, off); }
  float mu = s * (1.f / 512.f);
  float rs = rsqrtf(q * (1.f / 512.f) - mu * mu + 512.0f);
  float4 ga = *(const float4*)(g2 + lane * 8);
  float4 gb = *(const float4*)(g2 + lane * 8 + 4);
  float4 ba = *(const float4*)(bb2 + lane * 8);
  float4 bb = *(const float4*)(bb2 + lane * 8 + 4);
  float4 o0, o1;
  o0.x = (f[0] - mu) * rs * ga.x + ba.x;
  o0.y = (f[1] - mu) * rs * ga.y + ba.y;
  o0.z = (f[2] - mu) * rs * ga.z + ba.z;
  o0.w = (f[3] - mu) * rs * ga.w + ba.w;
  o1.x = (f[4] - mu) * rs * gb.x + bb.x;
  o1.y = (f[5] - mu) * rs * gb.y + bb.y;
  o1.z = (f[6] - mu) * rs * gb.z + bb.z;
  o1.w = (f[7] - mu) * rs * gb.w + bb.w;
  float* orow = out + row * 512 + lane * 8;
  *(float4*)orow = o0;
  *(float4*)(orow + 4) = o1;
}

extern "C" void kernel_launch(void* const* d_in, const int* in_sizes, int n_in,
                              void* d_out, int out_size, void* d_ws, size_t ws_size,
                              hipStream_t stream) {
  const float* x   = (const float*)d_in[0];
  const float* Wq  = (const float*)d_in[1];
  const float* Wk  = (const float*)d_in[2];
  const float* Wv  = (const float*)d_in[3];
  const float* Wp  = (const float*)d_in[4];
  const float* bp  = (const float*)d_in[5];
  const float* W1  = (const float*)d_in[6];
  const float* b1  = (const float*)d_in[7];
  const float* W2  = (const float*)d_in[8];
  const float* b2  = (const float*)d_in[9];
  const float* g1  = (const float*)d_in[10];
  const float* bb1 = (const float*)d_in[11];
  const float* g2  = (const float*)d_in[12];
  const float* bb2 = (const float*)d_in[13];
  float* out = (float*)d_out;

  char* ws = (char*)d_ws;
  u16* Gbf  = (u16*)ws;                      // 32KB (region reserved 256KB)
  u16* WvpT = (u16*)(ws + (256 << 10));      // 128KB
  u16* W1T  = (u16*)(ws + (1 << 20));        // 2MB
  u16* W2T  = (u16*)(ws + (3 << 20));        // 2MB
  u16* Z    = (u16*)(ws + (5 << 20));        // 16MB
  u16* X1   = (u16*)(ws + (21 << 20));       // 64MB (becomes y bf16 after kff2)
  u16* H    = (u16*)(ws + (85ull << 20));    // H slice region

  hipLaunchKernelGGL(kprep_G,   dim3(64),        dim3(256), 0, stream, Wq, Wk, Gbf);
  hipLaunchKernelGGL(kprep_Wvp, dim3(256),       dim3(256), 0, stream, Wv, Wp, WvpT);
  hipLaunchKernelGGL(kprep_W1T, dim3(32, 8),     dim3(256), 0, stream, W1, W1T);
  hipLaunchKernelGGL(kprep_W2T, dim3(32, 8),     dim3(256), 0, stream, W2, W2T);
  hipLaunchKernelGGL(ktoken,    dim3(4096),      dim3(256), 0, stream, x, Gbf, Z);
  hipLaunchKernelGGL(kattn,     dim3(1024),      dim3(512), 0, stream, Z, WvpT, bp, x, g1, bb1, X1);

  // S>=4 so each H slice (<=64MB) is L3-resident between kff1 and kff2
  const size_t hbase = 85ull << 20;
  int S = 64;
  for (int c = 4; c <= 64; c <<= 1) {
    if (hbase + (268435456ull / (size_t)c) <= ws_size) { S = c; break; }
  }
  int Ms = MROWS / S;   // 16384 rows at S=4
  for (int s = 0; s < S; ++s) {
    const u16* x1s = X1 + (size_t)s * Ms * 512;
    hipLaunchKernelGGL(kff1, dim3((Ms / 256) * 16), dim3(512), 0, stream, x1s, W1T, b1, H);
    hipLaunchKernelGGL(kff2, dim3((Ms / 128) * 4),  dim3(256), 0, stream, H, W2T, b2,
                       X1 + (size_t)s * Ms * 512);
  }
  hipLaunchKernelGGL(kln2, dim3(8192), dim3(512), 0, stream, X1, g2, bb2, out);
}